// Round 1
// baseline (2934.456 us; speedup 1.0000x reference)
//
#include <hip/hip_runtime.h>
#include <math.h>

#define NHEADS 2

// ---------------------------------------------------------------------------
// QKV projection GEMM.
// X[m=(b,l), k] = fm[b, k, l]  (fm = f1 for q-rows, f2/f3 for k/v rows)
// Y[m, n] = X @ w_in^T + b_in ; n -> (which, h, d); scatter to Q/K/V [B*NH, L, dh]
// Q is pre-scaled by 1/sqrt(dh).
// ---------------------------------------------------------------------------
__global__ __launch_bounds__(256) void qkv_proj_kernel(
    const float* __restrict__ fq, const float* __restrict__ fkv,
    const float* __restrict__ w, const float* __restrict__ bias,
    float* __restrict__ Qo, float* __restrict__ Ko, float* __restrict__ Vo,
    int C, int L, int dh, float qscale)
{
    const int n0 = blockIdx.x * 32;
    const int m0 = blockIdx.y * 32;
    __shared__ float Xs[32][33];
    __shared__ float Ws[32][33];
    const int t = threadIdx.x;
    const int tx = t & 31;   // n_local (output contiguous in d)
    const int ty = t >> 5;   // m base
    const float* __restrict__ fm = (n0 < C) ? fq : fkv;
    float acc[4] = {0.f, 0.f, 0.f, 0.f};
    const int nkt = C >> 5;
    for (int kt = 0; kt < nkt; ++kt) {
        int idx = t;
        #pragma unroll
        for (int p = 0; p < 4; ++p, idx += 256) {
            int ml = idx & 31, kl = idx >> 5;
            int m = m0 + ml; int b = m / L; int l = m - b * L;
            Xs[ml][kl] = fm[(size_t)(b * C + kt * 32 + kl) * L + l];
        }
        idx = t;
        #pragma unroll
        for (int p = 0; p < 4; ++p, idx += 256) {
            int kl = idx & 31, nl = idx >> 5;
            Ws[nl][kl] = w[(size_t)(n0 + nl) * C + kt * 32 + kl];
        }
        __syncthreads();
        #pragma unroll
        for (int kk = 0; kk < 32; ++kk) {
            float wv = Ws[tx][kk];
            #pragma unroll
            for (int j = 0; j < 4; ++j)
                acc[j] += Xs[ty + 8 * j][kk] * wv;
        }
        __syncthreads();
    }
    const int n = n0 + tx;
    const int which = n / C;
    const int co = n - which * C;
    const int h = co / dh;
    const int d = co - h * dh;
    const float bv = bias[n];
    float* dst = (which == 0) ? Qo : (which == 1 ? Ko : Vo);
    const float sc = (which == 0) ? qscale : 1.0f;
    #pragma unroll
    for (int j = 0; j < 4; ++j) {
        int m = m0 + ty + 8 * j;
        int b = m / L; int l = m - b * L;
        dst[((size_t)(b * NHEADS + h) * L + l) * dh + d] = (acc[j] + bv) * sc;
    }
}

// ---------------------------------------------------------------------------
// Flash attention, fp32. One block = one (bh, 32-query tile). 256 threads.
// 8 threads per query row; thread handles s in {sub+8j}. O chunk interleaved
// d = 8c+sub to keep PV LDS reads conflict-free.
// ---------------------------------------------------------------------------
template <int DH>
__global__ __launch_bounds__(256) void flash_kernel(
    const float* __restrict__ Q, const float* __restrict__ K,
    const float* __restrict__ V, float* __restrict__ O, int L, int S)
{
    constexpr int CHK = DH / 8;
    const int nQT = L >> 5;
    const int qt = blockIdx.x % nQT;
    const int bh = blockIdx.x / nQT;
    const int q0 = qt * 32;
    __shared__ float Qs[32][DH + 1];
    __shared__ float Ks[32][DH + 1];
    __shared__ float Vs[32][DH + 1];
    __shared__ float Ps[32][33];
    const int t = threadIdx.x;
    const int row = t >> 3;
    const int sub = t & 7;

    for (int idx = t; idx < 32 * DH; idx += 256) {
        int r = idx / DH, d = idx % DH;
        Qs[r][d] = Q[((size_t)bh * L + q0 + r) * DH + d];
    }
    float m_i = -1e30f, l_i = 0.f;
    float o[CHK];
    #pragma unroll
    for (int c = 0; c < CHK; ++c) o[c] = 0.f;
    __syncthreads();

    for (int s0 = 0; s0 < S; s0 += 32) {
        for (int idx = t; idx < 32 * DH; idx += 256) {
            int r = idx / DH, d = idx % DH;
            Ks[r][d] = K[((size_t)bh * S + s0 + r) * DH + d];
            Vs[r][d] = V[((size_t)bh * S + s0 + r) * DH + d];
        }
        __syncthreads();

        float sc[4] = {0.f, 0.f, 0.f, 0.f};
        #pragma unroll 8
        for (int d = 0; d < DH; ++d) {
            float qv = Qs[row][d];
            #pragma unroll
            for (int j = 0; j < 4; ++j)
                sc[j] += qv * Ks[sub + 8 * j][d];
        }
        float tm = fmaxf(fmaxf(sc[0], sc[1]), fmaxf(sc[2], sc[3]));
        #pragma unroll
        for (int off = 1; off < 8; off <<= 1)
            tm = fmaxf(tm, __shfl_xor(tm, off));
        float m_new = fmaxf(m_i, tm);
        float alpha = __expf(m_i - m_new);
        float p[4], ts = 0.f;
        #pragma unroll
        for (int j = 0; j < 4; ++j) { p[j] = __expf(sc[j] - m_new); ts += p[j]; }
        #pragma unroll
        for (int off = 1; off < 8; off <<= 1)
            ts += __shfl_xor(ts, off);
        l_i = l_i * alpha + ts;
        #pragma unroll
        for (int c = 0; c < CHK; ++c) o[c] *= alpha;
        m_i = m_new;
        #pragma unroll
        for (int j = 0; j < 4; ++j) Ps[row][sub + 8 * j] = p[j];
        __syncthreads();

        #pragma unroll 4
        for (int s = 0; s < 32; ++s) {
            float pv = Ps[row][s];
            #pragma unroll
            for (int c = 0; c < CHK; ++c)
                o[c] += pv * Vs[s][8 * c + sub];
        }
        __syncthreads();
    }
    const float inv = 1.f / l_i;
    #pragma unroll
    for (int c = 0; c < CHK; ++c)
        O[((size_t)bh * L + q0 + row) * DH + 8 * c + sub] = o[c] * inv;
}

// ---------------------------------------------------------------------------
// out_proj GEMM: att[b, n, l] = sum_k attn[(b,h(k)), l, d(k)] * w[n,k] + bias[n]
// Output written channel-major [B, C, L] for the squeeze.
// ---------------------------------------------------------------------------
__global__ __launch_bounds__(256) void out_proj_kernel(
    const float* __restrict__ attn, const float* __restrict__ w,
    const float* __restrict__ bias, float* __restrict__ out,
    int C, int L, int dh)
{
    const int n0 = blockIdx.x * 32;
    const int m0 = blockIdx.y * 32;
    __shared__ float Xs[32][33];
    __shared__ float Ws[32][33];
    const int t = threadIdx.x;
    const int tx = t & 31;   // m_local (output contiguous in l)
    const int ty = t >> 5;
    float acc[4] = {0.f, 0.f, 0.f, 0.f};
    const int nkt = C >> 5;
    for (int kt = 0; kt < nkt; ++kt) {
        int idx = t;
        #pragma unroll
        for (int p = 0; p < 4; ++p, idx += 256) {
            int kl = idx & 31, ml = idx >> 5;
            int m = m0 + ml; int b = m / L; int l = m - b * L;
            int k = kt * 32 + kl; int h = k / dh; int d = k - h * dh;
            Xs[ml][kl] = attn[((size_t)(b * NHEADS + h) * L + l) * dh + d];
        }
        idx = t;
        #pragma unroll
        for (int p = 0; p < 4; ++p, idx += 256) {
            int kl = idx & 31, nl = idx >> 5;
            Ws[nl][kl] = w[(size_t)(n0 + nl) * C + kt * 32 + kl];
        }
        __syncthreads();
        #pragma unroll
        for (int kk = 0; kk < 32; ++kk) {
            float xv = Xs[tx][kk];
            #pragma unroll
            for (int j = 0; j < 4; ++j)
                acc[j] += xv * Ws[ty + 8 * j][kk];
        }
        __syncthreads();
    }
    const int m = m0 + tx; const int b = m / L; const int l = m - b * L;
    #pragma unroll
    for (int j = 0; j < 4; ++j) {
        int n = n0 + ty + 8 * j;
        out[(size_t)(b * C + n) * L + l] = acc[j] + bias[n];
    }
}

// ---------------------------------------------------------------------------
// Squeeze 1x1 conv: out[b,n,l] = sum_{k<3C} sqw[n,k]*cat[b,k,l] + sqb[n]
// cat gathered from f1 / att1 / att2 (all [B, C, L]).
// ---------------------------------------------------------------------------
__global__ __launch_bounds__(256) void squeeze_kernel(
    const float* __restrict__ f1, const float* __restrict__ a1,
    const float* __restrict__ a2, const float* __restrict__ w,
    const float* __restrict__ bias, float* __restrict__ out, int C, int L)
{
    const int n0 = blockIdx.x * 32;
    const int m0 = blockIdx.y * 32;
    __shared__ float Xs[32][33];
    __shared__ float Ws[32][33];
    const int t = threadIdx.x;
    const int tx = t & 31;   // m_local
    const int ty = t >> 5;
    float acc[4] = {0.f, 0.f, 0.f, 0.f};
    const int Ktot = 3 * C;
    for (int kt = 0; kt < (Ktot >> 5); ++kt) {
        int idx = t;
        #pragma unroll
        for (int p = 0; p < 4; ++p, idx += 256) {
            int ml = idx & 31, kl = idx >> 5;
            int m = m0 + ml; int b = m / L; int l = m - b * L;
            int k = kt * 32 + kl;
            const float* src = (k < C) ? f1 : ((k < 2 * C) ? a1 : a2);
            int c = (k < C) ? k : ((k < 2 * C) ? (k - C) : (k - 2 * C));
            Xs[ml][kl] = src[(size_t)(b * C + c) * L + l];
        }
        idx = t;
        #pragma unroll
        for (int p = 0; p < 4; ++p, idx += 256) {
            int kl = idx & 31, nl = idx >> 5;
            Ws[nl][kl] = w[(size_t)(n0 + nl) * Ktot + kt * 32 + kl];
        }
        __syncthreads();
        #pragma unroll
        for (int kk = 0; kk < 32; ++kk) {
            float xv = Xs[tx][kk];
            #pragma unroll
            for (int j = 0; j < 4; ++j)
                acc[j] += xv * Ws[ty + 8 * j][kk];
        }
        __syncthreads();
    }
    const int m = m0 + tx; const int b = m / L; const int l = m - b * L;
    #pragma unroll
    for (int j = 0; j < 4; ++j) {
        int n = n0 + ty + 8 * j;
        out[(size_t)(b * C + n) * L + l] = acc[j] + bias[n];
    }
}

// ---------------------------------------------------------------------------

static void run_flash(int dh, int nblk, const float* Q, const float* K,
                      const float* V, float* O, int L, hipStream_t stream)
{
    if (dh == 64)
        flash_kernel<64><<<nblk, 256, 0, stream>>>(Q, K, V, O, L, L);
    else if (dh == 128)
        flash_kernel<128><<<nblk, 256, 0, stream>>>(Q, K, V, O, L, L);
    else
        flash_kernel<256><<<nblk, 256, 0, stream>>>(Q, K, V, O, L, L);
}

extern "C" void kernel_launch(void* const* d_in, const int* in_sizes, int n_in,
                              void* d_out, int out_size, void* d_ws, size_t ws_size,
                              hipStream_t stream)
{
    static const int CHs[4] = {64, 128, 256, 512};
    static const int HWs[4] = {128, 64, 32, 16};

    const float* f1[4] = {(const float*)d_in[0], (const float*)d_in[1],
                          (const float*)d_in[2], (const float*)d_in[3]};
    // setup_inputs dict order: f2_1, f3_1, f2_2, f3_2, f2_3, f3_3
    const float* f2[4] = {nullptr, (const float*)d_in[4], (const float*)d_in[6],
                          (const float*)d_in[8]};
    const float* f3[4] = {nullptr, (const float*)d_in[5], (const float*)d_in[7],
                          (const float*)d_in[9]};

    // level 0: pass-through
    size_t out0_elems = (size_t)in_sizes[0];
    hipMemcpyAsync(d_out, d_in[0], out0_elems * sizeof(float),
                   hipMemcpyDeviceToDevice, stream);

    // workspace partition (max level-1 buffer = 2*128*4096 = 1,048,576 floats)
    const size_t MAXE = (size_t)2 * 128 * 4096;
    float* Qb = (float*)d_ws;
    float* Kb = Qb + MAXE;
    float* Vb = Kb + MAXE;
    float* An = Vb + MAXE;
    float* A1 = An + MAXE;
    float* A2 = A1 + MAXE;

    size_t outOff = out0_elems;
    for (int lvl = 1; lvl <= 3; ++lvl) {
        const int C = CHs[lvl];
        const int Hs = HWs[lvl];
        const int L = Hs * Hs;
        const int dh = C / NHEADS;
        const int M = 2 * L;  // B*L
        const float qscale = 1.0f / sqrtf((float)dh);
        const int bi = 10 + (lvl - 1) * 10;
        const float* a12w  = (const float*)d_in[bi + 0];
        const float* a12b  = (const float*)d_in[bi + 1];
        const float* a12ow = (const float*)d_in[bi + 2];
        const float* a12ob = (const float*)d_in[bi + 3];
        const float* a13w  = (const float*)d_in[bi + 4];
        const float* a13b  = (const float*)d_in[bi + 5];
        const float* a13ow = (const float*)d_in[bi + 6];
        const float* a13ob = (const float*)d_in[bi + 7];
        const float* sqw   = (const float*)d_in[bi + 8];
        const float* sqb   = (const float*)d_in[bi + 9];

        dim3 gp(3 * C / 32, M / 32);
        dim3 go(C / 32, M / 32);
        const int nblk = 2 * NHEADS * (L / 32);

        // attention 1: Q from f1, K/V from f2
        qkv_proj_kernel<<<gp, 256, 0, stream>>>(f1[lvl], f2[lvl], a12w, a12b,
                                                Qb, Kb, Vb, C, L, dh, qscale);
        run_flash(dh, nblk, Qb, Kb, Vb, An, L, stream);
        out_proj_kernel<<<go, 256, 0, stream>>>(An, a12ow, a12ob, A1, C, L, dh);

        // attention 2: Q from f1, K/V from f3
        qkv_proj_kernel<<<gp, 256, 0, stream>>>(f1[lvl], f3[lvl], a13w, a13b,
                                                Qb, Kb, Vb, C, L, dh, qscale);
        run_flash(dh, nblk, Qb, Kb, Vb, An, L, stream);
        out_proj_kernel<<<go, 256, 0, stream>>>(An, a13ow, a13ob, A2, C, L, dh);

        // squeeze into d_out
        squeeze_kernel<<<go, 256, 0, stream>>>(f1[lvl], A1, A2, sqw, sqb,
                                               (float*)d_out + outOff, C, L);
        outOff += (size_t)2 * C * L;
    }
}

// Round 2
// 880.275 us; speedup vs baseline: 3.3336x; 3.3336x over previous
//
#include <hip/hip_runtime.h>
#include <hip/hip_bf16.h>
#include <math.h>

#define NHEADS 2

typedef unsigned short u16;
typedef __attribute__((ext_vector_type(8))) unsigned short u16x8;
typedef __attribute__((ext_vector_type(4))) unsigned short u16x4;
typedef __attribute__((ext_vector_type(8))) short short8;
typedef __attribute__((ext_vector_type(4))) float f32x4;

__device__ __forceinline__ u16 f2bf(float x) {
    __hip_bfloat16 h = __float2bfloat16(x);
    return __builtin_bit_cast(unsigned short, h);
}

// ---------------------------------------------------------------------------
// QKV projection GEMM (fp32 in, bf16 out).
// X[m=(b,l), k] = fm[b, k, l]; Y = X @ w_in^T + b_in; scatter to Q/K/V
// [B*NH, L, dh] in bf16. Q pre-scaled by qscale (includes LOG2E).
// ---------------------------------------------------------------------------
__global__ __launch_bounds__(256) void qkv_proj_kernel(
    const float* __restrict__ fq, const float* __restrict__ fkv,
    const float* __restrict__ w, const float* __restrict__ bias,
    u16* __restrict__ Qo, u16* __restrict__ Ko, u16* __restrict__ Vo,
    int C, int L, int dh, float qscale)
{
    const int n0 = blockIdx.x * 32;
    const int m0 = blockIdx.y * 32;
    __shared__ float Xs[32][33];
    __shared__ float Ws[32][33];
    const int t = threadIdx.x;
    const int tx = t & 31;   // n_local (output contiguous in d)
    const int ty = t >> 5;   // m base
    const float* __restrict__ fm = (n0 < C) ? fq : fkv;
    float acc[4] = {0.f, 0.f, 0.f, 0.f};
    const int nkt = C >> 5;
    for (int kt = 0; kt < nkt; ++kt) {
        int idx = t;
        #pragma unroll
        for (int p = 0; p < 4; ++p, idx += 256) {
            int ml = idx & 31, kl = idx >> 5;
            int m = m0 + ml; int b = m / L; int l = m - b * L;
            Xs[ml][kl] = fm[(size_t)(b * C + kt * 32 + kl) * L + l];
        }
        idx = t;
        #pragma unroll
        for (int p = 0; p < 4; ++p, idx += 256) {
            int kl = idx & 31, nl = idx >> 5;
            Ws[nl][kl] = w[(size_t)(n0 + nl) * C + kt * 32 + kl];
        }
        __syncthreads();
        #pragma unroll
        for (int kk = 0; kk < 32; ++kk) {
            float wv = Ws[tx][kk];
            #pragma unroll
            for (int j = 0; j < 4; ++j)
                acc[j] += Xs[ty + 8 * j][kk] * wv;
        }
        __syncthreads();
    }
    const int n = n0 + tx;
    const int which = n / C;
    const int co = n - which * C;
    const int h = co / dh;
    const int d = co - h * dh;
    const float bv = bias[n];
    u16* dst = (which == 0) ? Qo : (which == 1 ? Ko : Vo);
    const float sc = (which == 0) ? qscale : 1.0f;
    #pragma unroll
    for (int j = 0; j < 4; ++j) {
        int m = m0 + ty + 8 * j;
        int b = m / L; int l = m - b * L;
        dst[((size_t)(b * NHEADS + h) * L + l) * dh + d] = f2bf((acc[j] + bv) * sc);
    }
}

// ---------------------------------------------------------------------------
// MFMA flash attention, bf16 inputs, fp32 out.
// Block = 128 threads (2 waves). Each wave owns NQS*16 q-rows. KBLK = 64.
// Swapped QK^T: S^T = mfma(K_frag, Q_frag) so softmax rows are lane-local.
// V staged transposed in LDS; P round-trips LDS as bf16 (b64-packed writes).
// Q in log2-scale (qscale includes LOG2E) -> exp2 softmax.
// ---------------------------------------------------------------------------
template <int DH, int NQS, int PRE>
__global__ __launch_bounds__(128) void flash_mfma(
    const u16* __restrict__ Q, const u16* __restrict__ K,
    const u16* __restrict__ V, float* __restrict__ O, int L, int S)
{
    constexpr int KB = 64;               // s-tile
    constexpr int QW = NQS * 16;         // q rows per wave
    constexpr int QB = 2 * QW;           // q rows per block
    constexpr int DH8 = DH / 8;
    constexpr int KC = (KB * DH8) / 128; // K 16B-chunks per thread
    constexpr int VU = (16 * DH8) / 128; // V 4-row units per thread
    constexpr int NKK = DH / 32;         // k-steps in QK^T
    constexpr int NNT = DH / 16;         // d-subtiles in PV
    constexpr int PADS = KB + 8;

    __shared__ __align__(16) u16 Ks[KB][DH + 8];
    __shared__ __align__(16) u16 Vt[DH][PADS];
    __shared__ __align__(16) u16 Ps[2][QW][PADS];

    const int nQT = L / QB;
    const int qt = blockIdx.x % nQT;
    const int bh = blockIdx.x / nQT;
    const int tid = threadIdx.x;
    const int wv = tid >> 6;
    const int lane = tid & 63;
    const int lo = lane & 15;
    const int hi = lane >> 4;
    const int q0 = qt * QB + wv * QW;

    // Q fragments (held in registers for the whole kernel)
    short8 qf[NQS][NKK];
    #pragma unroll
    for (int qs = 0; qs < NQS; ++qs)
        #pragma unroll
        for (int kk = 0; kk < NKK; ++kk)
            qf[qs][kk] = *(const short8*)&Q[((size_t)bh * L + q0 + qs * 16 + lo) * DH + kk * 32 + hi * 8];

    f32x4 acc[NQS][NNT];
    #pragma unroll
    for (int qs = 0; qs < NQS; ++qs)
        #pragma unroll
        for (int nt = 0; nt < NNT; ++nt)
            #pragma unroll
            for (int r = 0; r < 4; ++r) acc[qs][nt][r] = 0.f;
    float m_i[NQS], l_i[NQS];
    #pragma unroll
    for (int qs = 0; qs < NQS; ++qs) { m_i[qs] = -1e30f; l_i[qs] = 0.f; }

    const int NT = S / KB;
    u16x8 kreg[PRE ? KC : 1];
    u16x8 vreg[PRE ? VU : 1][4];

    const u16* Kbase = K + (size_t)bh * S * DH;
    const u16* Vbase = V + (size_t)bh * S * DH;

    if (PRE) {
        #pragma unroll
        for (int i = 0; i < KC; ++i) {
            int idx = tid + i * 128;
            kreg[i] = *(const u16x8*)&Kbase[(size_t)(idx / DH8) * DH + (idx % DH8) * 8];
        }
        #pragma unroll
        for (int u = 0; u < VU; ++u) {
            int uu = tid + u * 128;
            int d0 = (uu % DH8) * 8, s0 = (uu / DH8) * 4;
            #pragma unroll
            for (int si = 0; si < 4; ++si)
                vreg[u][si] = *(const u16x8*)&Vbase[(size_t)(s0 + si) * DH + d0];
        }
    }

    for (int t = 0; t < NT; ++t) {
        __syncthreads();   // previous tile's LDS reads complete
        if (PRE) {
            #pragma unroll
            for (int i = 0; i < KC; ++i) {
                int idx = tid + i * 128;
                *(u16x8*)&Ks[idx / DH8][(idx % DH8) * 8] = kreg[i];
            }
            #pragma unroll
            for (int u = 0; u < VU; ++u) {
                int uu = tid + u * 128;
                int d0 = (uu % DH8) * 8, s0 = (uu / DH8) * 4;
                #pragma unroll
                for (int j = 0; j < 8; ++j) {
                    u16x4 wj = {vreg[u][0][j], vreg[u][1][j], vreg[u][2][j], vreg[u][3][j]};
                    *(u16x4*)&Vt[d0 + j][s0] = wj;
                }
            }
        } else {
            const u16* Kp = Kbase + (size_t)t * KB * DH;
            const u16* Vp = Vbase + (size_t)t * KB * DH;
            #pragma unroll
            for (int i = 0; i < KC; ++i) {
                int idx = tid + i * 128;
                *(u16x8*)&Ks[idx / DH8][(idx % DH8) * 8] =
                    *(const u16x8*)&Kp[(size_t)(idx / DH8) * DH + (idx % DH8) * 8];
            }
            #pragma unroll
            for (int u = 0; u < VU; ++u) {
                int uu = tid + u * 128;
                int d0 = (uu % DH8) * 8, s0 = (uu / DH8) * 4;
                u16x8 v0 = *(const u16x8*)&Vp[(size_t)(s0 + 0) * DH + d0];
                u16x8 v1 = *(const u16x8*)&Vp[(size_t)(s0 + 1) * DH + d0];
                u16x8 v2 = *(const u16x8*)&Vp[(size_t)(s0 + 2) * DH + d0];
                u16x8 v3 = *(const u16x8*)&Vp[(size_t)(s0 + 3) * DH + d0];
                #pragma unroll
                for (int j = 0; j < 8; ++j) {
                    u16x4 wj = {v0[j], v1[j], v2[j], v3[j]};
                    *(u16x4*)&Vt[d0 + j][s0] = wj;
                }
            }
        }
        __syncthreads();   // staged tile visible

        if (PRE && t + 1 < NT) {   // issue next tile's loads; latency hides under compute
            const u16* Kp = Kbase + (size_t)(t + 1) * KB * DH;
            const u16* Vp = Vbase + (size_t)(t + 1) * KB * DH;
            #pragma unroll
            for (int i = 0; i < KC; ++i) {
                int idx = tid + i * 128;
                kreg[i] = *(const u16x8*)&Kp[(size_t)(idx / DH8) * DH + (idx % DH8) * 8];
            }
            #pragma unroll
            for (int u = 0; u < VU; ++u) {
                int uu = tid + u * 128;
                int d0 = (uu % DH8) * 8, s0 = (uu / DH8) * 4;
                #pragma unroll
                for (int si = 0; si < 4; ++si)
                    vreg[u][si] = *(const u16x8*)&Vp[(size_t)(s0 + si) * DH + d0];
            }
        }

        // ---- QK^T (swapped): sacc[st][qs] holds S^T[s=st*16+hi*4+r][q=qs*16+lo]
        f32x4 sacc[4][NQS];
        #pragma unroll
        for (int st = 0; st < 4; ++st)
            #pragma unroll
            for (int qs = 0; qs < NQS; ++qs)
                #pragma unroll
                for (int r = 0; r < 4; ++r) sacc[st][qs][r] = 0.f;
        #pragma unroll
        for (int st = 0; st < 4; ++st) {
            #pragma unroll
            for (int kk = 0; kk < NKK; ++kk) {
                short8 a = *(const short8*)&Ks[st * 16 + lo][kk * 32 + hi * 8];
                #pragma unroll
                for (int qs = 0; qs < NQS; ++qs)
                    sacc[st][qs] = __builtin_amdgcn_mfma_f32_16x16x32_bf16(
                        a, qf[qs][kk], sacc[st][qs], 0, 0, 0);
            }
        }

        // ---- online softmax (log2 domain), P -> LDS as bf16
        #pragma unroll
        for (int qs = 0; qs < NQS; ++qs) {
            float tm = -1e30f;
            #pragma unroll
            for (int st = 0; st < 4; ++st)
                #pragma unroll
                for (int r = 0; r < 4; ++r) tm = fmaxf(tm, sacc[st][qs][r]);
            tm = fmaxf(tm, __shfl_xor(tm, 16));
            tm = fmaxf(tm, __shfl_xor(tm, 32));
            float mn = fmaxf(m_i[qs], tm);
            float alpha = __builtin_amdgcn_exp2f(m_i[qs] - mn);
            m_i[qs] = mn;
            float ts = 0.f;
            #pragma unroll
            for (int st = 0; st < 4; ++st) {
                float p0 = __builtin_amdgcn_exp2f(sacc[st][qs][0] - mn);
                float p1 = __builtin_amdgcn_exp2f(sacc[st][qs][1] - mn);
                float p2 = __builtin_amdgcn_exp2f(sacc[st][qs][2] - mn);
                float p3 = __builtin_amdgcn_exp2f(sacc[st][qs][3] - mn);
                ts += (p0 + p1) + (p2 + p3);
                u16x4 wp = {f2bf(p0), f2bf(p1), f2bf(p2), f2bf(p3)};
                *(u16x4*)&Ps[wv][qs * 16 + lo][st * 16 + hi * 4] = wp;
            }
            ts += __shfl_xor(ts, 16);
            ts += __shfl_xor(ts, 32);
            l_i[qs] = l_i[qs] * alpha + ts;
            float ar[4];
            #pragma unroll
            for (int r = 0; r < 4; ++r) ar[r] = __shfl(alpha, hi * 4 + r);
            #pragma unroll
            for (int nt = 0; nt < NNT; ++nt)
                #pragma unroll
                for (int r = 0; r < 4; ++r) acc[qs][nt][r] *= ar[r];
        }

        // ---- PV: acc[qs][nt] += P(16xKB) @ V(KBxDH)
        #pragma unroll
        for (int ks = 0; ks < 2; ++ks) {
            short8 pa[NQS];
            #pragma unroll
            for (int qs = 0; qs < NQS; ++qs)
                pa[qs] = *(const short8*)&Ps[wv][qs * 16 + lo][ks * 32 + hi * 8];
            #pragma unroll
            for (int nt = 0; nt < NNT; ++nt) {
                short8 vb = *(const short8*)&Vt[nt * 16 + lo][ks * 32 + hi * 8];
                #pragma unroll
                for (int qs = 0; qs < NQS; ++qs)
                    acc[qs][nt] = __builtin_amdgcn_mfma_f32_16x16x32_bf16(
                        pa[qs], vb, acc[qs][nt], 0, 0, 0);
            }
        }
    }

    // ---- epilogue: O = acc / l
    #pragma unroll
    for (int qs = 0; qs < NQS; ++qs) {
        float inv = 1.0f / l_i[qs];
        float ir[4];
        #pragma unroll
        for (int r = 0; r < 4; ++r) ir[r] = __shfl(inv, hi * 4 + r);
        #pragma unroll
        for (int nt = 0; nt < NNT; ++nt)
            #pragma unroll
            for (int r = 0; r < 4; ++r)
                O[((size_t)bh * L + q0 + qs * 16 + hi * 4 + r) * DH + nt * 16 + lo] =
                    acc[qs][nt][r] * ir[r];
    }
}

// ---------------------------------------------------------------------------
// out_proj GEMM (fp32): att[b, n, l] = sum_k attn[(b,h),l,d] * w[n,k] + bias[n]
// ---------------------------------------------------------------------------
__global__ __launch_bounds__(256) void out_proj_kernel(
    const float* __restrict__ attn, const float* __restrict__ w,
    const float* __restrict__ bias, float* __restrict__ out,
    int C, int L, int dh)
{
    const int n0 = blockIdx.x * 32;
    const int m0 = blockIdx.y * 32;
    __shared__ float Xs[32][33];
    __shared__ float Ws[32][33];
    const int t = threadIdx.x;
    const int tx = t & 31;
    const int ty = t >> 5;
    float acc[4] = {0.f, 0.f, 0.f, 0.f};
    const int nkt = C >> 5;
    for (int kt = 0; kt < nkt; ++kt) {
        int idx = t;
        #pragma unroll
        for (int p = 0; p < 4; ++p, idx += 256) {
            int kl = idx & 31, ml = idx >> 5;
            int m = m0 + ml; int b = m / L; int l = m - b * L;
            int k = kt * 32 + kl; int h = k / dh; int d = k - h * dh;
            Xs[ml][kl] = attn[((size_t)(b * NHEADS + h) * L + l) * dh + d];
        }
        idx = t;
        #pragma unroll
        for (int p = 0; p < 4; ++p, idx += 256) {
            int kl = idx & 31, nl = idx >> 5;
            Ws[nl][kl] = w[(size_t)(n0 + nl) * C + kt * 32 + kl];
        }
        __syncthreads();
        #pragma unroll
        for (int kk = 0; kk < 32; ++kk) {
            float xv = Xs[tx][kk];
            #pragma unroll
            for (int j = 0; j < 4; ++j)
                acc[j] += xv * Ws[ty + 8 * j][kk];
        }
        __syncthreads();
    }
    const int m = m0 + tx; const int b = m / L; const int l = m - b * L;
    #pragma unroll
    for (int j = 0; j < 4; ++j) {
        int n = n0 + ty + 8 * j;
        out[(size_t)(b * C + n) * L + l] = acc[j] + bias[n];
    }
}

// ---------------------------------------------------------------------------
// Squeeze 1x1 conv (fp32)
// ---------------------------------------------------------------------------
__global__ __launch_bounds__(256) void squeeze_kernel(
    const float* __restrict__ f1, const float* __restrict__ a1,
    const float* __restrict__ a2, const float* __restrict__ w,
    const float* __restrict__ bias, float* __restrict__ out, int C, int L)
{
    const int n0 = blockIdx.x * 32;
    const int m0 = blockIdx.y * 32;
    __shared__ float Xs[32][33];
    __shared__ float Ws[32][33];
    const int t = threadIdx.x;
    const int tx = t & 31;
    const int ty = t >> 5;
    float acc[4] = {0.f, 0.f, 0.f, 0.f};
    const int Ktot = 3 * C;
    for (int kt = 0; kt < (Ktot >> 5); ++kt) {
        int idx = t;
        #pragma unroll
        for (int p = 0; p < 4; ++p, idx += 256) {
            int ml = idx & 31, kl = idx >> 5;
            int m = m0 + ml; int b = m / L; int l = m - b * L;
            int k = kt * 32 + kl;
            const float* src = (k < C) ? f1 : ((k < 2 * C) ? a1 : a2);
            int c = (k < C) ? k : ((k < 2 * C) ? (k - C) : (k - 2 * C));
            Xs[ml][kl] = src[(size_t)(b * C + c) * L + l];
        }
        idx = t;
        #pragma unroll
        for (int p = 0; p < 4; ++p, idx += 256) {
            int kl = idx & 31, nl = idx >> 5;
            Ws[nl][kl] = w[(size_t)(n0 + nl) * Ktot + kt * 32 + kl];
        }
        __syncthreads();
        #pragma unroll
        for (int kk = 0; kk < 32; ++kk) {
            float xv = Xs[tx][kk];
            #pragma unroll
            for (int j = 0; j < 4; ++j)
                acc[j] += xv * Ws[ty + 8 * j][kk];
        }
        __syncthreads();
    }
    const int m = m0 + tx; const int b = m / L; const int l = m - b * L;
    #pragma unroll
    for (int j = 0; j < 4; ++j) {
        int n = n0 + ty + 8 * j;
        out[(size_t)(b * C + n) * L + l] = acc[j] + bias[n];
    }
}

// ---------------------------------------------------------------------------

static void run_flash(int dh, const u16* Q, const u16* K, const u16* V,
                      float* O, int L, hipStream_t stream)
{
    const int BH = 2 * NHEADS;
    if (dh == 64)
        flash_mfma<64, 2, 1><<<BH * (L / 64), 128, 0, stream>>>(Q, K, V, O, L, L);
    else if (dh == 128)
        flash_mfma<128, 2, 1><<<BH * (L / 64), 128, 0, stream>>>(Q, K, V, O, L, L);
    else
        flash_mfma<256, 1, 0><<<BH * (L / 32), 128, 0, stream>>>(Q, K, V, O, L, L);
}

extern "C" void kernel_launch(void* const* d_in, const int* in_sizes, int n_in,
                              void* d_out, int out_size, void* d_ws, size_t ws_size,
                              hipStream_t stream)
{
    static const int CHs[4] = {64, 128, 256, 512};
    static const int HWs[4] = {128, 64, 32, 16};

    const float* f1[4] = {(const float*)d_in[0], (const float*)d_in[1],
                          (const float*)d_in[2], (const float*)d_in[3]};
    const float* f2[4] = {nullptr, (const float*)d_in[4], (const float*)d_in[6],
                          (const float*)d_in[8]};
    const float* f3[4] = {nullptr, (const float*)d_in[5], (const float*)d_in[7],
                          (const float*)d_in[9]};

    // level 0: pass-through
    size_t out0_elems = (size_t)in_sizes[0];
    hipMemcpyAsync(d_out, d_in[0], out0_elems * sizeof(float),
                   hipMemcpyDeviceToDevice, stream);

    // workspace partition (slot = 1M floats; Q/K/V use them as bf16)
    const size_t MAXE = (size_t)2 * 128 * 4096;
    float* ws = (float*)d_ws;
    u16*   Qb = (u16*)(ws);
    u16*   Kb = (u16*)(ws + MAXE);
    u16*   Vb = (u16*)(ws + 2 * MAXE);
    float* An = ws + 3 * MAXE;
    float* A1 = ws + 4 * MAXE;
    float* A2 = ws + 5 * MAXE;

    const float LOG2E = 1.44269504088896340736f;

    size_t outOff = out0_elems;
    for (int lvl = 1; lvl <= 3; ++lvl) {
        const int C = CHs[lvl];
        const int Hs = HWs[lvl];
        const int L = Hs * Hs;
        const int dh = C / NHEADS;
        const int M = 2 * L;  // B*L
        const float qscale = LOG2E / sqrtf((float)dh);
        const int bi = 10 + (lvl - 1) * 10;
        const float* a12w  = (const float*)d_in[bi + 0];
        const float* a12b  = (const float*)d_in[bi + 1];
        const float* a12ow = (const float*)d_in[bi + 2];
        const float* a12ob = (const float*)d_in[bi + 3];
        const float* a13w  = (const float*)d_in[bi + 4];
        const float* a13b  = (const float*)d_in[bi + 5];
        const float* a13ow = (const float*)d_in[bi + 6];
        const float* a13ob = (const float*)d_in[bi + 7];
        const float* sqw   = (const float*)d_in[bi + 8];
        const float* sqb   = (const float*)d_in[bi + 9];

        dim3 gp(3 * C / 32, M / 32);
        dim3 go(C / 32, M / 32);

        // attention 1: Q from f1, K/V from f2
        qkv_proj_kernel<<<gp, 256, 0, stream>>>(f1[lvl], f2[lvl], a12w, a12b,
                                                Qb, Kb, Vb, C, L, dh, qscale);
        run_flash(dh, Qb, Kb, Vb, An, L, stream);
        out_proj_kernel<<<go, 256, 0, stream>>>(An, a12ow, a12ob, A1, C, L, dh);

        // attention 2: Q from f1, K/V from f3
        qkv_proj_kernel<<<gp, 256, 0, stream>>>(f1[lvl], f3[lvl], a13w, a13b,
                                                Qb, Kb, Vb, C, L, dh, qscale);
        run_flash(dh, Qb, Kb, Vb, An, L, stream);
        out_proj_kernel<<<go, 256, 0, stream>>>(An, a13ow, a13ob, A2, C, L, dh);

        // squeeze into d_out
        squeeze_kernel<<<go, 256, 0, stream>>>(f1[lvl], A1, A2, sqw, sqb,
                                               (float*)d_out + outOff, C, L);
        outOff += (size_t)2 * C * L;
    }
}

// Round 3
// 504.725 us; speedup vs baseline: 5.8140x; 1.7441x over previous
//
#include <hip/hip_runtime.h>
#include <hip/hip_bf16.h>
#include <math.h>

#define NHEADS 2

typedef unsigned short u16;
typedef __attribute__((ext_vector_type(8))) unsigned short u16x8;
typedef __attribute__((ext_vector_type(4))) unsigned short u16x4;
typedef __attribute__((ext_vector_type(8))) short short8;
typedef __attribute__((ext_vector_type(4))) float f32x4;

__device__ __forceinline__ u16 f2bf(float x) {
    __hip_bfloat16 h = __float2bfloat16(x);
    return __builtin_bit_cast(unsigned short, h);
}

// ---------------------------------------------------------------------------
// Transpose + bf16 convert: f [b, c, l] fp32  ->  ft [b, l, c] bf16.
// grid (L/32, C/32, 2*3); z = which*2 + b.
// ---------------------------------------------------------------------------
__global__ __launch_bounds__(256) void transpose_bf16_kernel(
    const float* __restrict__ s0, const float* __restrict__ s1,
    const float* __restrict__ s2,
    u16* __restrict__ d0, u16* __restrict__ d1, u16* __restrict__ d2,
    int C, int L)
{
    const int z = blockIdx.z;
    const int which = z >> 1;
    const int b = z & 1;
    const float* __restrict__ src = (which == 0) ? s0 : (which == 1 ? s1 : s2);
    u16* __restrict__ dst = (which == 0) ? d0 : (which == 1 ? d1 : d2);
    const int l0 = blockIdx.x * 32;
    const int c0 = blockIdx.y * 32;
    __shared__ float Ts[32][33];
    const int t = threadIdx.x;
    const int x = t & 31, y = t >> 5;
    #pragma unroll
    for (int p = 0; p < 4; ++p)
        Ts[y + 8 * p][x] = src[((size_t)(b * C + c0 + y + 8 * p)) * L + l0 + x];
    __syncthreads();
    #pragma unroll
    for (int p = 0; p < 4; ++p)
        dst[((size_t)(b * L + l0 + y + 8 * p)) * C + c0 + x] = f2bf(Ts[x][y + 8 * p]);
}

// ---------------------------------------------------------------------------
// bf16 MFMA GEMM: out[n, m] = sum_k W[n,k] * X[m,k] + bias[n]
//   W fp32 [N][K] (converted to bf16 during staging), X bf16 rows contig in k.
// MODE 0 (qkv):    X = (n<C ? X0 : X1); scatter bf16 to Q/K/V [b*NH+h][l][d],
//                  q rows scaled by qscale.
// MODE 1 (proj):   out bf16 [m][N].
// MODE 2 (squeeze):X per-k-block from {X0,X1,X2} (row stride C); out fp32 [b][n][l].
// BM=BN=BK=64, 256 threads (4 waves, 2x2), register-prefetch staging.
// ---------------------------------------------------------------------------
template <int MODE>
__global__ __launch_bounds__(256) void gemm_bf16(
    const u16* __restrict__ X0, const u16* __restrict__ X1,
    const u16* __restrict__ X2,
    const float* __restrict__ W, const float* __restrict__ bias,
    void* __restrict__ out0, u16* __restrict__ out1, u16* __restrict__ out2,
    int M, int N, int K, int C, int L, int dh, float qscale)
{
    const int n0 = blockIdx.x * 64;
    const int m0 = blockIdx.y * 64;
    __shared__ __align__(16) u16 Xs[64][72];
    __shared__ __align__(16) u16 Ws[64][72];
    const int tid = threadIdx.x;
    const int wid = tid >> 6, lane = tid & 63;
    const int lo = lane & 15, hi = lane >> 4;
    const int wm = wid >> 1, wn = wid & 1;
    const int Kx = (MODE == 2) ? C : K;

    const u16* __restrict__ Xbase = (MODE == 0) ? ((n0 < C) ? X0 : X1) : X0;

    f32x4 acc[2][2];
    #pragma unroll
    for (int i = 0; i < 2; ++i)
        #pragma unroll
        for (int j = 0; j < 2; ++j)
            #pragma unroll
            for (int r = 0; r < 4; ++r) acc[i][j][r] = 0.f;

    u16x8 xreg[2];
    f32x4 wreg[4];

    auto load_x = [&](int k0) {
        const u16* src; int kl;
        if (MODE == 2) {
            int wk = k0 / C;
            src = (wk == 0) ? X0 : (wk == 1 ? X1 : X2);
            kl = k0 - wk * C;
        } else { src = Xbase; kl = k0; }
        #pragma unroll
        for (int p = 0; p < 2; ++p) {
            int c = tid + p * 256;
            int row = c >> 3, kc = c & 7;
            xreg[p] = *(const u16x8*)&src[(size_t)(m0 + row) * Kx + kl + kc * 8];
        }
    };
    auto load_w = [&](int k0) {
        #pragma unroll
        for (int p = 0; p < 4; ++p) {
            int c = tid + p * 256;
            int row = c >> 4, kc = c & 15;
            wreg[p] = *(const f32x4*)&W[(size_t)(n0 + row) * K + k0 + kc * 4];
        }
    };

    load_x(0);
    load_w(0);
    const int ns = K / 64;
    for (int s = 0; s < ns; ++s) {
        __syncthreads();
        #pragma unroll
        for (int p = 0; p < 2; ++p) {
            int c = tid + p * 256;
            int row = c >> 3, kc = c & 7;
            *(u16x8*)&Xs[row][kc * 8] = xreg[p];
        }
        #pragma unroll
        for (int p = 0; p < 4; ++p) {
            int c = tid + p * 256;
            int row = c >> 4, kc = c & 15;
            u16x4 cv = {f2bf(wreg[p][0]), f2bf(wreg[p][1]),
                        f2bf(wreg[p][2]), f2bf(wreg[p][3])};
            *(u16x4*)&Ws[row][kc * 4] = cv;
        }
        __syncthreads();
        if (s + 1 < ns) { load_x((s + 1) * 64); load_w((s + 1) * 64); }
        #pragma unroll
        for (int kk = 0; kk < 2; ++kk) {
            short8 wf0 = *(const short8*)&Ws[wn * 32 + lo][kk * 32 + hi * 8];
            short8 wf1 = *(const short8*)&Ws[wn * 32 + 16 + lo][kk * 32 + hi * 8];
            short8 xf0 = *(const short8*)&Xs[wm * 32 + lo][kk * 32 + hi * 8];
            short8 xf1 = *(const short8*)&Xs[wm * 32 + 16 + lo][kk * 32 + hi * 8];
            acc[0][0] = __builtin_amdgcn_mfma_f32_16x16x32_bf16(wf0, xf0, acc[0][0], 0, 0, 0);
            acc[0][1] = __builtin_amdgcn_mfma_f32_16x16x32_bf16(wf1, xf0, acc[0][1], 0, 0, 0);
            acc[1][0] = __builtin_amdgcn_mfma_f32_16x16x32_bf16(wf0, xf1, acc[1][0], 0, 0, 0);
            acc[1][1] = __builtin_amdgcn_mfma_f32_16x16x32_bf16(wf1, xf1, acc[1][1], 0, 0, 0);
        }
    }

    // epilogue: D[row n = hi*4+r (+nt*16+wn*32)][col m = lo (+mt*16+wm*32)]
    #pragma unroll
    for (int nt = 0; nt < 2; ++nt) {
        const int nb = n0 + wn * 32 + nt * 16 + hi * 4;
        const float b0 = bias[nb + 0], b1 = bias[nb + 1];
        const float b2 = bias[nb + 2], b3 = bias[nb + 3];
        if (MODE == 0) {
            const int which = nb / C;
            const int co = nb - which * C;
            const int h = co / dh;
            const int dd = co - h * dh;
            u16* dst = (which == 0) ? (u16*)out0 : (which == 1 ? out1 : out2);
            const float sc = (which == 0) ? qscale : 1.0f;
            #pragma unroll
            for (int mt = 0; mt < 2; ++mt) {
                int m = m0 + wm * 32 + mt * 16 + lo;
                int b_ = m / L; int l = m - b_ * L;
                u16x4 pk = {f2bf((acc[mt][nt][0] + b0) * sc),
                            f2bf((acc[mt][nt][1] + b1) * sc),
                            f2bf((acc[mt][nt][2] + b2) * sc),
                            f2bf((acc[mt][nt][3] + b3) * sc)};
                *(u16x4*)&dst[((size_t)(b_ * NHEADS + h) * L + l) * dh + dd] = pk;
            }
        } else if (MODE == 1) {
            u16* dst = (u16*)out0;
            #pragma unroll
            for (int mt = 0; mt < 2; ++mt) {
                int m = m0 + wm * 32 + mt * 16 + lo;
                u16x4 pk = {f2bf(acc[mt][nt][0] + b0), f2bf(acc[mt][nt][1] + b1),
                            f2bf(acc[mt][nt][2] + b2), f2bf(acc[mt][nt][3] + b3)};
                *(u16x4*)&dst[(size_t)m * N + nb] = pk;
            }
        } else {
            float* dst = (float*)out0;
            #pragma unroll
            for (int mt = 0; mt < 2; ++mt) {
                int m = m0 + wm * 32 + mt * 16 + lo;
                int b_ = m / L; int l = m - b_ * L;
                dst[((size_t)(b_ * C + nb + 0)) * L + l] = acc[mt][nt][0] + b0;
                dst[((size_t)(b_ * C + nb + 1)) * L + l] = acc[mt][nt][1] + b1;
                dst[((size_t)(b_ * C + nb + 2)) * L + l] = acc[mt][nt][2] + b2;
                dst[((size_t)(b_ * C + nb + 3)) * L + l] = acc[mt][nt][3] + b3;
            }
        }
    }
}

// ---------------------------------------------------------------------------
// MFMA flash attention, bf16 in, bf16 out in [b, l, (h,d)] layout.
// ---------------------------------------------------------------------------
template <int DH, int NQS, int PRE>
__global__ __launch_bounds__(128) void flash_mfma(
    const u16* __restrict__ Q, const u16* __restrict__ K,
    const u16* __restrict__ V, u16* __restrict__ O, int L, int S)
{
    constexpr int KB = 64;
    constexpr int QW = NQS * 16;
    constexpr int QB = 2 * QW;
    constexpr int DH8 = DH / 8;
    constexpr int KC = (KB * DH8) / 128;
    constexpr int VU = (16 * DH8) / 128;
    constexpr int NKK = DH / 32;
    constexpr int NNT = DH / 16;
    constexpr int PADS = KB + 8;

    __shared__ __align__(16) u16 Ks[KB][DH + 8];
    __shared__ __align__(16) u16 Vt[DH][PADS];
    __shared__ __align__(16) u16 Ps[2][QW][PADS];

    const int nQT = L / QB;
    const int qt = blockIdx.x % nQT;
    const int bh = blockIdx.x / nQT;
    const int tid = threadIdx.x;
    const int wv = tid >> 6;
    const int lane = tid & 63;
    const int lo = lane & 15;
    const int hi = lane >> 4;
    const int q0 = qt * QB + wv * QW;

    short8 qf[NQS][NKK];
    #pragma unroll
    for (int qs = 0; qs < NQS; ++qs)
        #pragma unroll
        for (int kk = 0; kk < NKK; ++kk)
            qf[qs][kk] = *(const short8*)&Q[((size_t)bh * L + q0 + qs * 16 + lo) * DH + kk * 32 + hi * 8];

    f32x4 acc[NQS][NNT];
    #pragma unroll
    for (int qs = 0; qs < NQS; ++qs)
        #pragma unroll
        for (int nt = 0; nt < NNT; ++nt)
            #pragma unroll
            for (int r = 0; r < 4; ++r) acc[qs][nt][r] = 0.f;
    float m_i[NQS], l_i[NQS];
    #pragma unroll
    for (int qs = 0; qs < NQS; ++qs) { m_i[qs] = -1e30f; l_i[qs] = 0.f; }

    const int NT = S / KB;
    u16x8 kreg[PRE ? KC : 1];
    u16x8 vreg[PRE ? VU : 1][4];

    const u16* Kbase = K + (size_t)bh * S * DH;
    const u16* Vbase = V + (size_t)bh * S * DH;

    if (PRE) {
        #pragma unroll
        for (int i = 0; i < KC; ++i) {
            int idx = tid + i * 128;
            kreg[i] = *(const u16x8*)&Kbase[(size_t)(idx / DH8) * DH + (idx % DH8) * 8];
        }
        #pragma unroll
        for (int u = 0; u < VU; ++u) {
            int uu = tid + u * 128;
            int d0 = (uu % DH8) * 8, s0 = (uu / DH8) * 4;
            #pragma unroll
            for (int si = 0; si < 4; ++si)
                vreg[u][si] = *(const u16x8*)&Vbase[(size_t)(s0 + si) * DH + d0];
        }
    }

    for (int t = 0; t < NT; ++t) {
        __syncthreads();
        if (PRE) {
            #pragma unroll
            for (int i = 0; i < KC; ++i) {
                int idx = tid + i * 128;
                *(u16x8*)&Ks[idx / DH8][(idx % DH8) * 8] = kreg[i];
            }
            #pragma unroll
            for (int u = 0; u < VU; ++u) {
                int uu = tid + u * 128;
                int d0 = (uu % DH8) * 8, s0 = (uu / DH8) * 4;
                #pragma unroll
                for (int j = 0; j < 8; ++j) {
                    u16x4 wj = {vreg[u][0][j], vreg[u][1][j], vreg[u][2][j], vreg[u][3][j]};
                    *(u16x4*)&Vt[d0 + j][s0] = wj;
                }
            }
        } else {
            const u16* Kp = Kbase + (size_t)t * KB * DH;
            const u16* Vp = Vbase + (size_t)t * KB * DH;
            #pragma unroll
            for (int i = 0; i < KC; ++i) {
                int idx = tid + i * 128;
                *(u16x8*)&Ks[idx / DH8][(idx % DH8) * 8] =
                    *(const u16x8*)&Kp[(size_t)(idx / DH8) * DH + (idx % DH8) * 8];
            }
            #pragma unroll
            for (int u = 0; u < VU; ++u) {
                int uu = tid + u * 128;
                int d0 = (uu % DH8) * 8, s0 = (uu / DH8) * 4;
                u16x8 v0 = *(const u16x8*)&Vp[(size_t)(s0 + 0) * DH + d0];
                u16x8 v1 = *(const u16x8*)&Vp[(size_t)(s0 + 1) * DH + d0];
                u16x8 v2 = *(const u16x8*)&Vp[(size_t)(s0 + 2) * DH + d0];
                u16x8 v3 = *(const u16x8*)&Vp[(size_t)(s0 + 3) * DH + d0];
                #pragma unroll
                for (int j = 0; j < 8; ++j) {
                    u16x4 wj = {v0[j], v1[j], v2[j], v3[j]};
                    *(u16x4*)&Vt[d0 + j][s0] = wj;
                }
            }
        }
        __syncthreads();

        if (PRE && t + 1 < NT) {
            const u16* Kp = Kbase + (size_t)(t + 1) * KB * DH;
            const u16* Vp = Vbase + (size_t)(t + 1) * KB * DH;
            #pragma unroll
            for (int i = 0; i < KC; ++i) {
                int idx = tid + i * 128;
                kreg[i] = *(const u16x8*)&Kp[(size_t)(idx / DH8) * DH + (idx % DH8) * 8];
            }
            #pragma unroll
            for (int u = 0; u < VU; ++u) {
                int uu = tid + u * 128;
                int d0 = (uu % DH8) * 8, s0 = (uu / DH8) * 4;
                #pragma unroll
                for (int si = 0; si < 4; ++si)
                    vreg[u][si] = *(const u16x8*)&Vp[(size_t)(s0 + si) * DH + d0];
            }
        }

        f32x4 sacc[4][NQS];
        #pragma unroll
        for (int st = 0; st < 4; ++st)
            #pragma unroll
            for (int qs = 0; qs < NQS; ++qs)
                #pragma unroll
                for (int r = 0; r < 4; ++r) sacc[st][qs][r] = 0.f;
        #pragma unroll
        for (int st = 0; st < 4; ++st) {
            #pragma unroll
            for (int kk = 0; kk < NKK; ++kk) {
                short8 a = *(const short8*)&Ks[st * 16 + lo][kk * 32 + hi * 8];
                #pragma unroll
                for (int qs = 0; qs < NQS; ++qs)
                    sacc[st][qs] = __builtin_amdgcn_mfma_f32_16x16x32_bf16(
                        a, qf[qs][kk], sacc[st][qs], 0, 0, 0);
            }
        }

        #pragma unroll
        for (int qs = 0; qs < NQS; ++qs) {
            float tm = -1e30f;
            #pragma unroll
            for (int st = 0; st < 4; ++st)
                #pragma unroll
                for (int r = 0; r < 4; ++r) tm = fmaxf(tm, sacc[st][qs][r]);
            tm = fmaxf(tm, __shfl_xor(tm, 16));
            tm = fmaxf(tm, __shfl_xor(tm, 32));
            float mn = fmaxf(m_i[qs], tm);
            float alpha = __builtin_amdgcn_exp2f(m_i[qs] - mn);
            m_i[qs] = mn;
            float ts = 0.f;
            #pragma unroll
            for (int st = 0; st < 4; ++st) {
                float p0 = __builtin_amdgcn_exp2f(sacc[st][qs][0] - mn);
                float p1 = __builtin_amdgcn_exp2f(sacc[st][qs][1] - mn);
                float p2 = __builtin_amdgcn_exp2f(sacc[st][qs][2] - mn);
                float p3 = __builtin_amdgcn_exp2f(sacc[st][qs][3] - mn);
                ts += (p0 + p1) + (p2 + p3);
                u16x4 wp = {f2bf(p0), f2bf(p1), f2bf(p2), f2bf(p3)};
                *(u16x4*)&Ps[wv][qs * 16 + lo][st * 16 + hi * 4] = wp;
            }
            ts += __shfl_xor(ts, 16);
            ts += __shfl_xor(ts, 32);
            l_i[qs] = l_i[qs] * alpha + ts;
            float ar[4];
            #pragma unroll
            for (int r = 0; r < 4; ++r) ar[r] = __shfl(alpha, hi * 4 + r);
            #pragma unroll
            for (int nt = 0; nt < NNT; ++nt)
                #pragma unroll
                for (int r = 0; r < 4; ++r) acc[qs][nt][r] *= ar[r];
        }

        #pragma unroll
        for (int ks = 0; ks < 2; ++ks) {
            short8 pa[NQS];
            #pragma unroll
            for (int qs = 0; qs < NQS; ++qs)
                pa[qs] = *(const short8*)&Ps[wv][qs * 16 + lo][ks * 32 + hi * 8];
            #pragma unroll
            for (int nt = 0; nt < NNT; ++nt) {
                short8 vb = *(const short8*)&Vt[nt * 16 + lo][ks * 32 + hi * 8];
                #pragma unroll
                for (int qs = 0; qs < NQS; ++qs)
                    acc[qs][nt] = __builtin_amdgcn_mfma_f32_16x16x32_bf16(
                        pa[qs], vb, acc[qs][nt], 0, 0, 0);
            }
        }
    }

    // epilogue: O[b, l, h, d] bf16
    const int b_ = bh / NHEADS, h_ = bh % NHEADS;
    #pragma unroll
    for (int qs = 0; qs < NQS; ++qs) {
        float inv = 1.0f / l_i[qs];
        float ir[4];
        #pragma unroll
        for (int r = 0; r < 4; ++r) ir[r] = __shfl(inv, hi * 4 + r);
        #pragma unroll
        for (int nt = 0; nt < NNT; ++nt)
            #pragma unroll
            for (int r = 0; r < 4; ++r) {
                int l = q0 + qs * 16 + hi * 4 + r;
                O[(((size_t)b_ * L + l) * NHEADS + h_) * DH + nt * 16 + lo] =
                    f2bf(acc[qs][nt][r] * ir[r]);
            }
    }
}

// ---------------------------------------------------------------------------

static void run_flash(int dh, const u16* Q, const u16* K, const u16* V,
                      u16* O, int L, hipStream_t stream)
{
    const int BH = 2 * NHEADS;
    if (dh == 64)
        flash_mfma<64, 2, 1><<<BH * (L / 64), 128, 0, stream>>>(Q, K, V, O, L, L);
    else if (dh == 128)
        flash_mfma<128, 2, 1><<<BH * (L / 64), 128, 0, stream>>>(Q, K, V, O, L, L);
    else
        flash_mfma<256, 1, 0><<<BH * (L / 32), 128, 0, stream>>>(Q, K, V, O, L, L);
}

extern "C" void kernel_launch(void* const* d_in, const int* in_sizes, int n_in,
                              void* d_out, int out_size, void* d_ws, size_t ws_size,
                              hipStream_t stream)
{
    static const int CHs[4] = {64, 128, 256, 512};
    static const int HWs[4] = {128, 64, 32, 16};

    const float* f1[4] = {(const float*)d_in[0], (const float*)d_in[1],
                          (const float*)d_in[2], (const float*)d_in[3]};
    const float* f2[4] = {nullptr, (const float*)d_in[4], (const float*)d_in[6],
                          (const float*)d_in[8]};
    const float* f3[4] = {nullptr, (const float*)d_in[5], (const float*)d_in[7],
                          (const float*)d_in[9]};

    // level 0: pass-through
    size_t out0_elems = (size_t)in_sizes[0];
    hipMemcpyAsync(d_out, d_in[0], out0_elems * sizeof(float),
                   hipMemcpyDeviceToDevice, stream);

    // workspace: 9 bf16 slots of 2*4096*128 elems (18 MB total)
    const size_t SL = (size_t)2 * 4096 * 128;
    u16* wsu = (u16*)d_ws;
    u16* f1t = wsu + 0 * SL;
    u16* f2t = wsu + 1 * SL;
    u16* f3t = wsu + 2 * SL;
    u16* Qb  = wsu + 3 * SL;
    u16* Kb  = wsu + 4 * SL;
    u16* Vb  = wsu + 5 * SL;
    u16* An  = wsu + 6 * SL;
    u16* A1t = wsu + 7 * SL;
    u16* A2t = wsu + 8 * SL;

    const float LOG2E = 1.44269504088896340736f;

    size_t outOff = out0_elems;
    for (int lvl = 1; lvl <= 3; ++lvl) {
        const int C = CHs[lvl];
        const int Hs = HWs[lvl];
        const int L = Hs * Hs;
        const int dh = C / NHEADS;
        const int M = 2 * L;  // B*L
        const float qscale = LOG2E / sqrtf((float)dh);
        const int bi = 10 + (lvl - 1) * 10;
        const float* a12w  = (const float*)d_in[bi + 0];
        const float* a12b  = (const float*)d_in[bi + 1];
        const float* a12ow = (const float*)d_in[bi + 2];
        const float* a12ob = (const float*)d_in[bi + 3];
        const float* a13w  = (const float*)d_in[bi + 4];
        const float* a13b  = (const float*)d_in[bi + 5];
        const float* a13ow = (const float*)d_in[bi + 6];
        const float* a13ob = (const float*)d_in[bi + 7];
        const float* sqw   = (const float*)d_in[bi + 8];
        const float* sqb   = (const float*)d_in[bi + 9];

        // transpose f1/f2/f3 -> bf16 [b, l, c]
        dim3 tg(L / 32, C / 32, 6);
        transpose_bf16_kernel<<<tg, 256, 0, stream>>>(f1[lvl], f2[lvl], f3[lvl],
                                                      f1t, f2t, f3t, C, L);

        dim3 gq(3 * C / 64, M / 64);
        dim3 gp(C / 64, M / 64);

        // attention 1: Q from f1t, K/V from f2t
        gemm_bf16<0><<<gq, 256, 0, stream>>>(f1t, f2t, nullptr, a12w, a12b,
                                             (void*)Qb, Kb, Vb,
                                             M, 3 * C, C, C, L, dh, qscale);
        run_flash(dh, Qb, Kb, Vb, An, L, stream);
        gemm_bf16<1><<<gp, 256, 0, stream>>>(An, nullptr, nullptr, a12ow, a12ob,
                                             (void*)A1t, nullptr, nullptr,
                                             M, C, C, C, L, dh, 1.0f);

        // attention 2: Q from f1t, K/V from f3t
        gemm_bf16<0><<<gq, 256, 0, stream>>>(f1t, f3t, nullptr, a13w, a13b,
                                             (void*)Qb, Kb, Vb,
                                             M, 3 * C, C, C, L, dh, qscale);
        run_flash(dh, Qb, Kb, Vb, An, L, stream);
        gemm_bf16<1><<<gp, 256, 0, stream>>>(An, nullptr, nullptr, a13ow, a13ob,
                                             (void*)A2t, nullptr, nullptr,
                                             M, C, C, C, L, dh, 1.0f);

        // squeeze into d_out (fp32 [b, n, l])
        gemm_bf16<2><<<gp, 256, 0, stream>>>(f1t, A1t, A2t, sqw, sqb,
                                             (void*)((float*)d_out + outOff),
                                             nullptr, nullptr,
                                             M, C, 3 * C, C, L, dh, 1.0f);
        outOff += (size_t)2 * C * L;
    }
}

// Round 4
// 453.961 us; speedup vs baseline: 6.4641x; 1.1118x over previous
//
#include <hip/hip_runtime.h>
#include <hip/hip_bf16.h>
#include <math.h>

#define NHEADS 2

typedef unsigned short u16;
typedef __attribute__((ext_vector_type(8))) unsigned short u16x8;
typedef __attribute__((ext_vector_type(4))) unsigned short u16x4;
typedef __attribute__((ext_vector_type(8))) short short8;
typedef __attribute__((ext_vector_type(4))) float f32x4;

__device__ __forceinline__ u16 f2bf(float x) {
    __hip_bfloat16 h = __float2bfloat16(x);
    return __builtin_bit_cast(unsigned short, h);
}

// ---------------------------------------------------------------------------
// Transpose + bf16 convert: f [b, c, l] fp32  ->  ft [b, l, c] bf16.
// ---------------------------------------------------------------------------
__global__ __launch_bounds__(256) void transpose_bf16_kernel(
    const float* __restrict__ s0, const float* __restrict__ s1,
    const float* __restrict__ s2,
    u16* __restrict__ d0, u16* __restrict__ d1, u16* __restrict__ d2,
    int C, int L)
{
    const int z = blockIdx.z;
    const int which = z >> 1;
    const int b = z & 1;
    const float* __restrict__ src = (which == 0) ? s0 : (which == 1 ? s1 : s2);
    u16* __restrict__ dst = (which == 0) ? d0 : (which == 1 ? d1 : d2);
    const int l0 = blockIdx.x * 32;
    const int c0 = blockIdx.y * 32;
    __shared__ float Ts[32][33];
    const int t = threadIdx.x;
    const int x = t & 31, y = t >> 5;
    #pragma unroll
    for (int p = 0; p < 4; ++p)
        Ts[y + 8 * p][x] = src[((size_t)(b * C + c0 + y + 8 * p)) * L + l0 + x];
    __syncthreads();
    #pragma unroll
    for (int p = 0; p < 4; ++p)
        dst[((size_t)(b * L + l0 + y + 8 * p)) * C + c0 + x] = f2bf(Ts[x][y + 8 * p]);
}

// ---------------------------------------------------------------------------
// bf16 MFMA GEMM (same as round 3): out[n,m] = sum_k W[n,k]*X[m,k] + bias[n]
// ---------------------------------------------------------------------------
template <int MODE>
__global__ __launch_bounds__(256) void gemm_bf16(
    const u16* __restrict__ X0, const u16* __restrict__ X1,
    const u16* __restrict__ X2,
    const float* __restrict__ W, const float* __restrict__ bias,
    void* __restrict__ out0, u16* __restrict__ out1, u16* __restrict__ out2,
    int M, int N, int K, int C, int L, int dh, float qscale)
{
    const int n0 = blockIdx.x * 64;
    const int m0 = blockIdx.y * 64;
    __shared__ __align__(16) u16 Xs[64][72];
    __shared__ __align__(16) u16 Ws[64][72];
    const int tid = threadIdx.x;
    const int wid = tid >> 6, lane = tid & 63;
    const int lo = lane & 15, hi = lane >> 4;
    const int wm = wid >> 1, wn = wid & 1;
    const int Kx = (MODE == 2) ? C : K;

    const u16* __restrict__ Xbase = (MODE == 0) ? ((n0 < C) ? X0 : X1) : X0;

    f32x4 acc[2][2];
    #pragma unroll
    for (int i = 0; i < 2; ++i)
        #pragma unroll
        for (int j = 0; j < 2; ++j)
            #pragma unroll
            for (int r = 0; r < 4; ++r) acc[i][j][r] = 0.f;

    u16x8 xreg[2];
    f32x4 wreg[4];

    auto load_x = [&](int k0) {
        const u16* src; int kl;
        if (MODE == 2) {
            int wk = k0 / C;
            src = (wk == 0) ? X0 : (wk == 1 ? X1 : X2);
            kl = k0 - wk * C;
        } else { src = Xbase; kl = k0; }
        #pragma unroll
        for (int p = 0; p < 2; ++p) {
            int c = tid + p * 256;
            int row = c >> 3, kc = c & 7;
            xreg[p] = *(const u16x8*)&src[(size_t)(m0 + row) * Kx + kl + kc * 8];
        }
    };
    auto load_w = [&](int k0) {
        #pragma unroll
        for (int p = 0; p < 4; ++p) {
            int c = tid + p * 256;
            int row = c >> 4, kc = c & 15;
            wreg[p] = *(const f32x4*)&W[(size_t)(n0 + row) * K + k0 + kc * 4];
        }
    };

    load_x(0);
    load_w(0);
    const int ns = K / 64;
    for (int s = 0; s < ns; ++s) {
        __syncthreads();
        #pragma unroll
        for (int p = 0; p < 2; ++p) {
            int c = tid + p * 256;
            int row = c >> 3, kc = c & 7;
            *(u16x8*)&Xs[row][kc * 8] = xreg[p];
        }
        #pragma unroll
        for (int p = 0; p < 4; ++p) {
            int c = tid + p * 256;
            int row = c >> 4, kc = c & 15;
            u16x4 cv = {f2bf(wreg[p][0]), f2bf(wreg[p][1]),
                        f2bf(wreg[p][2]), f2bf(wreg[p][3])};
            *(u16x4*)&Ws[row][kc * 4] = cv;
        }
        __syncthreads();
        if (s + 1 < ns) { load_x((s + 1) * 64); load_w((s + 1) * 64); }
        #pragma unroll
        for (int kk = 0; kk < 2; ++kk) {
            short8 wf0 = *(const short8*)&Ws[wn * 32 + lo][kk * 32 + hi * 8];
            short8 wf1 = *(const short8*)&Ws[wn * 32 + 16 + lo][kk * 32 + hi * 8];
            short8 xf0 = *(const short8*)&Xs[wm * 32 + lo][kk * 32 + hi * 8];
            short8 xf1 = *(const short8*)&Xs[wm * 32 + 16 + lo][kk * 32 + hi * 8];
            acc[0][0] = __builtin_amdgcn_mfma_f32_16x16x32_bf16(wf0, xf0, acc[0][0], 0, 0, 0);
            acc[0][1] = __builtin_amdgcn_mfma_f32_16x16x32_bf16(wf1, xf0, acc[0][1], 0, 0, 0);
            acc[1][0] = __builtin_amdgcn_mfma_f32_16x16x32_bf16(wf0, xf1, acc[1][0], 0, 0, 0);
            acc[1][1] = __builtin_amdgcn_mfma_f32_16x16x32_bf16(wf1, xf1, acc[1][1], 0, 0, 0);
        }
    }

    #pragma unroll
    for (int nt = 0; nt < 2; ++nt) {
        const int nb = n0 + wn * 32 + nt * 16 + hi * 4;
        const float b0 = bias[nb + 0], b1 = bias[nb + 1];
        const float b2 = bias[nb + 2], b3 = bias[nb + 3];
        if (MODE == 0) {
            const int which = nb / C;
            const int co = nb - which * C;
            const int h = co / dh;
            const int dd = co - h * dh;
            u16* dst = (which == 0) ? (u16*)out0 : (which == 1 ? out1 : out2);
            const float sc = (which == 0) ? qscale : 1.0f;
            #pragma unroll
            for (int mt = 0; mt < 2; ++mt) {
                int m = m0 + wm * 32 + mt * 16 + lo;
                int b_ = m / L; int l = m - b_ * L;
                u16x4 pk = {f2bf((acc[mt][nt][0] + b0) * sc),
                            f2bf((acc[mt][nt][1] + b1) * sc),
                            f2bf((acc[mt][nt][2] + b2) * sc),
                            f2bf((acc[mt][nt][3] + b3) * sc)};
                *(u16x4*)&dst[((size_t)(b_ * NHEADS + h) * L + l) * dh + dd] = pk;
            }
        } else if (MODE == 1) {
            u16* dst = (u16*)out0;
            #pragma unroll
            for (int mt = 0; mt < 2; ++mt) {
                int m = m0 + wm * 32 + mt * 16 + lo;
                u16x4 pk = {f2bf(acc[mt][nt][0] + b0), f2bf(acc[mt][nt][1] + b1),
                            f2bf(acc[mt][nt][2] + b2), f2bf(acc[mt][nt][3] + b3)};
                *(u16x4*)&dst[(size_t)m * N + nb] = pk;
            }
        } else {
            float* dst = (float*)out0;
            #pragma unroll
            for (int mt = 0; mt < 2; ++mt) {
                int m = m0 + wm * 32 + mt * 16 + lo;
                int b_ = m / L; int l = m - b_ * L;
                dst[((size_t)(b_ * C + nb + 0)) * L + l] = acc[mt][nt][0] + b0;
                dst[((size_t)(b_ * C + nb + 1)) * L + l] = acc[mt][nt][1] + b1;
                dst[((size_t)(b_ * C + nb + 2)) * L + l] = acc[mt][nt][2] + b2;
                dst[((size_t)(b_ * C + nb + 3)) * L + l] = acc[mt][nt][3] + b3;
            }
        }
    }
}

// ---------------------------------------------------------------------------
// Level-1 flash: 256 threads = 4 waves = 2 q-groups x 2 s-parities.
// Double-buffered pair staging (1 barrier / 2 tiles), XOR-swizzled V^T LDS
// (conflict-free writes AND reads), fp32 cross-parity merge epilogue.
// DH = 64 only. Q pre-scaled by LOG2E/sqrt(dh) -> exp2 softmax.
// ---------------------------------------------------------------------------
template <int DH>
__global__ __launch_bounds__(256) void flash_split(
    const u16* __restrict__ Q, const u16* __restrict__ K,
    const u16* __restrict__ V, u16* __restrict__ O, int L, int S)
{
    constexpr int KB = 64;
    constexpr int NQS = 2;
    constexpr int QW = 32;
    constexpr int QB = 64;
    constexpr int NKK = DH / 32;   // 2
    constexpr int NNT = DH / 16;   // 4
    constexpr int KPAD = DH + 8;   // 72

    __shared__ __align__(16) u16 Ks[2][2][KB][KPAD];   // [dbuf][parity]
    __shared__ __align__(16) u16 Vt[2][2][DH][KB];     // swizzled V^T
    __shared__ __align__(16) u16 Ps[4][QW][KB + 8];
    __shared__ float MrgAcc[2][QW][DH + 4];
    __shared__ float MrgML[2][2][QW];

    const int nQT = L / QB;
    const int qt = blockIdx.x % nQT;
    const int bh = blockIdx.x / nQT;
    const int tid = threadIdx.x;
    const int w = tid >> 6;
    const int lane = tid & 63;
    const int lo = lane & 15, hi = lane >> 4;
    const int qg = w & 1, par = w >> 1;
    const int q0 = qt * QB + qg * QW;

    // ---- Q fragments in registers
    short8 qf[NQS][NKK];
    #pragma unroll
    for (int qs = 0; qs < NQS; ++qs)
        #pragma unroll
        for (int kk = 0; kk < NKK; ++kk)
            qf[qs][kk] = *(const short8*)&Q[((size_t)bh * L + q0 + qs * 16 + lo) * DH + kk * 32 + hi * 8];

    f32x4 acc[NQS][NNT];
    #pragma unroll
    for (int qs = 0; qs < NQS; ++qs)
        #pragma unroll
        for (int nt = 0; nt < NNT; ++nt)
            #pragma unroll
            for (int r = 0; r < 4; ++r) acc[qs][nt][r] = 0.f;
    float m_i[NQS], l_i[NQS];
    #pragma unroll
    for (int qs = 0; qs < NQS; ++qs) { m_i[qs] = -1e30f; l_i[qs] = 0.f; }

    const u16* Kbase = K + (size_t)bh * S * DH;
    const u16* Vbase = V + (size_t)bh * S * DH;

    // staging role: this thread stages parity pp of each pair
    const int pp = tid >> 7;
    const int u = tid & 127;
    const int sK = u >> 1, dK = (u & 1) * 32;            // K: 4x16B along row sK
    const int dV0 = (u & 7) * 8, sV0 = (u >> 3) * 4;     // V: 4 rows x 8 d

    u16x8 kreg[4];
    u16x8 vreg[4];

    auto loadpair = [&](int pair) {
        const u16* Kp = Kbase + (size_t)(2 * pair + pp) * KB * DH;
        const u16* Vp = Vbase + (size_t)(2 * pair + pp) * KB * DH;
        #pragma unroll
        for (int c = 0; c < 4; ++c)
            kreg[c] = *(const u16x8*)&Kp[(size_t)sK * DH + dK + 8 * c];
        #pragma unroll
        for (int si = 0; si < 4; ++si)
            vreg[si] = *(const u16x8*)&Vp[(size_t)(sV0 + si) * DH + dV0];
    };
    auto writepair = [&](int buf) {
        #pragma unroll
        for (int c = 0; c < 4; ++c)
            *(u16x8*)&Ks[buf][pp][sK][dK + 8 * c] = kreg[c];
        #pragma unroll
        for (int j = 0; j < 8; ++j) {
            int d = dV0 + j;
            int g = ((d >> 3) ^ d) & 7;
            int scol = (sV0 & 7) | ((((sV0 >> 3) ^ g) & 7) << 3);
            u16x4 wj = {vreg[0][j], vreg[1][j], vreg[2][j], vreg[3][j]};
            *(u16x4*)&Vt[buf][pp][d][scol] = wj;
        }
    };

    const int NT = S / KB;
    const int NS = NT / 2;

    loadpair(0);
    writepair(0);
    __syncthreads();

    for (int ss = 0; ss < NS; ++ss) {
        const int cur = ss & 1;
        if (ss + 1 < NS) loadpair(ss + 1);

        // ---- QK^T (swapped) from Ks[cur][par]
        f32x4 sacc[4][NQS];
        #pragma unroll
        for (int st = 0; st < 4; ++st)
            #pragma unroll
            for (int qs = 0; qs < NQS; ++qs)
                #pragma unroll
                for (int r = 0; r < 4; ++r) sacc[st][qs][r] = 0.f;
        #pragma unroll
        for (int st = 0; st < 4; ++st) {
            #pragma unroll
            for (int kk = 0; kk < NKK; ++kk) {
                short8 a = *(const short8*)&Ks[cur][par][st * 16 + lo][kk * 32 + hi * 8];
                #pragma unroll
                for (int qs = 0; qs < NQS; ++qs)
                    sacc[st][qs] = __builtin_amdgcn_mfma_f32_16x16x32_bf16(
                        a, qf[qs][kk], sacc[st][qs], 0, 0, 0);
            }
        }

        // ---- online softmax (log2 domain), P -> LDS bf16
        #pragma unroll
        for (int qs = 0; qs < NQS; ++qs) {
            float tm = -1e30f;
            #pragma unroll
            for (int st = 0; st < 4; ++st)
                #pragma unroll
                for (int r = 0; r < 4; ++r) tm = fmaxf(tm, sacc[st][qs][r]);
            tm = fmaxf(tm, __shfl_xor(tm, 16));
            tm = fmaxf(tm, __shfl_xor(tm, 32));
            float mn = fmaxf(m_i[qs], tm);
            float alpha = __builtin_amdgcn_exp2f(m_i[qs] - mn);
            m_i[qs] = mn;
            float ts = 0.f;
            #pragma unroll
            for (int st = 0; st < 4; ++st) {
                float p0 = __builtin_amdgcn_exp2f(sacc[st][qs][0] - mn);
                float p1 = __builtin_amdgcn_exp2f(sacc[st][qs][1] - mn);
                float p2 = __builtin_amdgcn_exp2f(sacc[st][qs][2] - mn);
                float p3 = __builtin_amdgcn_exp2f(sacc[st][qs][3] - mn);
                ts += (p0 + p1) + (p2 + p3);
                u16x4 wp = {f2bf(p0), f2bf(p1), f2bf(p2), f2bf(p3)};
                *(u16x4*)&Ps[w][qs * 16 + lo][st * 16 + hi * 4] = wp;
            }
            ts += __shfl_xor(ts, 16);
            ts += __shfl_xor(ts, 32);
            l_i[qs] = l_i[qs] * alpha + ts;
            float ar[4];
            #pragma unroll
            for (int r = 0; r < 4; ++r) ar[r] = __shfl(alpha, hi * 4 + r);
            #pragma unroll
            for (int nt = 0; nt < NNT; ++nt)
                #pragma unroll
                for (int r = 0; r < 4; ++r) acc[qs][nt][r] *= ar[r];
        }

        // ---- PV from swizzled Vt[cur][par]
        #pragma unroll
        for (int ks = 0; ks < 2; ++ks) {
            short8 pa[NQS];
            #pragma unroll
            for (int qs = 0; qs < NQS; ++qs)
                pa[qs] = *(const short8*)&Ps[w][qs * 16 + lo][ks * 32 + hi * 8];
            #pragma unroll
            for (int nt = 0; nt < NNT; ++nt) {
                int d = nt * 16 + lo;
                int g = ((d >> 3) ^ d) & 7;
                int scol = (((4 * ks + hi) ^ g) & 7) << 3;
                short8 vb = *(const short8*)&Vt[cur][par][d][scol];
                #pragma unroll
                for (int qs = 0; qs < NQS; ++qs)
                    acc[qs][nt] = __builtin_amdgcn_mfma_f32_16x16x32_bf16(
                        pa[qs], vb, acc[qs][nt], 0, 0, 0);
            }
        }

        if (ss + 1 < NS) writepair(cur ^ 1);
        __syncthreads();
    }

    // ---- cross-parity merge, O write by par==0 waves
    if (par == 1) {
        #pragma unroll
        for (int qs = 0; qs < NQS; ++qs) {
            #pragma unroll
            for (int nt = 0; nt < NNT; ++nt)
                #pragma unroll
                for (int r = 0; r < 4; ++r)
                    MrgAcc[qg][qs * 16 + hi * 4 + r][nt * 16 + lo] = acc[qs][nt][r];
            if (hi == 0) {
                MrgML[qg][0][qs * 16 + lo] = m_i[qs];
                MrgML[qg][1][qs * 16 + lo] = l_i[qs];
            }
        }
    }
    __syncthreads();
    if (par == 0) {
        const int b_ = bh / NHEADS, h_ = bh % NHEADS;
        #pragma unroll
        for (int qs = 0; qs < NQS; ++qs) {
            float m2 = MrgML[qg][0][qs * 16 + lo];
            float l2 = MrgML[qg][1][qs * 16 + lo];
            float mn = fmaxf(m_i[qs], m2);
            float c1 = __builtin_amdgcn_exp2f(m_i[qs] - mn);
            float c2 = __builtin_amdgcn_exp2f(m2 - mn);
            float linv = 1.0f / (c1 * l_i[qs] + c2 * l2);
            c1 *= linv; c2 *= linv;
            float c1r[4], c2r[4];
            #pragma unroll
            for (int r = 0; r < 4; ++r) {
                c1r[r] = __shfl(c1, hi * 4 + r);
                c2r[r] = __shfl(c2, hi * 4 + r);
            }
            #pragma unroll
            for (int nt = 0; nt < NNT; ++nt)
                #pragma unroll
                for (int r = 0; r < 4; ++r) {
                    int l = q0 + qs * 16 + hi * 4 + r;
                    float ov = acc[qs][nt][r] * c1r[r] +
                               MrgAcc[qg][qs * 16 + hi * 4 + r][nt * 16 + lo] * c2r[r];
                    O[(((size_t)b_ * L + l) * NHEADS + h_) * DH + nt * 16 + lo] = f2bf(ov);
                }
        }
    }
}

// ---------------------------------------------------------------------------
// Levels 2/3 flash (round-3 kernel, unchanged): 128 threads, 2 waves.
// ---------------------------------------------------------------------------
template <int DH, int NQS, int PRE>
__global__ __launch_bounds__(128) void flash_mfma(
    const u16* __restrict__ Q, const u16* __restrict__ K,
    const u16* __restrict__ V, u16* __restrict__ O, int L, int S)
{
    constexpr int KB = 64;
    constexpr int QW = NQS * 16;
    constexpr int QB = 2 * QW;
    constexpr int DH8 = DH / 8;
    constexpr int KC = (KB * DH8) / 128;
    constexpr int VU = (16 * DH8) / 128;
    constexpr int NKK = DH / 32;
    constexpr int NNT = DH / 16;
    constexpr int PADS = KB + 8;

    __shared__ __align__(16) u16 Ks[KB][DH + 8];
    __shared__ __align__(16) u16 Vt[DH][PADS];
    __shared__ __align__(16) u16 Ps[2][QW][PADS];

    const int nQT = L / QB;
    const int qt = blockIdx.x % nQT;
    const int bh = blockIdx.x / nQT;
    const int tid = threadIdx.x;
    const int wv = tid >> 6;
    const int lane = tid & 63;
    const int lo = lane & 15;
    const int hi = lane >> 4;
    const int q0 = qt * QB + wv * QW;

    short8 qf[NQS][NKK];
    #pragma unroll
    for (int qs = 0; qs < NQS; ++qs)
        #pragma unroll
        for (int kk = 0; kk < NKK; ++kk)
            qf[qs][kk] = *(const short8*)&Q[((size_t)bh * L + q0 + qs * 16 + lo) * DH + kk * 32 + hi * 8];

    f32x4 acc[NQS][NNT];
    #pragma unroll
    for (int qs = 0; qs < NQS; ++qs)
        #pragma unroll
        for (int nt = 0; nt < NNT; ++nt)
            #pragma unroll
            for (int r = 0; r < 4; ++r) acc[qs][nt][r] = 0.f;
    float m_i[NQS], l_i[NQS];
    #pragma unroll
    for (int qs = 0; qs < NQS; ++qs) { m_i[qs] = -1e30f; l_i[qs] = 0.f; }

    const int NT = S / KB;
    u16x8 kreg[PRE ? KC : 1];
    u16x8 vreg[PRE ? VU : 1][4];

    const u16* Kbase = K + (size_t)bh * S * DH;
    const u16* Vbase = V + (size_t)bh * S * DH;

    if (PRE) {
        #pragma unroll
        for (int i = 0; i < KC; ++i) {
            int idx = tid + i * 128;
            kreg[i] = *(const u16x8*)&Kbase[(size_t)(idx / DH8) * DH + (idx % DH8) * 8];
        }
        #pragma unroll
        for (int u = 0; u < VU; ++u) {
            int uu = tid + u * 128;
            int d0 = (uu % DH8) * 8, s0 = (uu / DH8) * 4;
            #pragma unroll
            for (int si = 0; si < 4; ++si)
                vreg[u][si] = *(const u16x8*)&Vbase[(size_t)(s0 + si) * DH + d0];
        }
    }

    for (int t = 0; t < NT; ++t) {
        __syncthreads();
        if (PRE) {
            #pragma unroll
            for (int i = 0; i < KC; ++i) {
                int idx = tid + i * 128;
                *(u16x8*)&Ks[idx / DH8][(idx % DH8) * 8] = kreg[i];
            }
            #pragma unroll
            for (int u = 0; u < VU; ++u) {
                int uu = tid + u * 128;
                int d0 = (uu % DH8) * 8, s0 = (uu / DH8) * 4;
                #pragma unroll
                for (int j = 0; j < 8; ++j) {
                    u16x4 wj = {vreg[u][0][j], vreg[u][1][j], vreg[u][2][j], vreg[u][3][j]};
                    *(u16x4*)&Vt[d0 + j][s0] = wj;
                }
            }
        } else {
            const u16* Kp = Kbase + (size_t)t * KB * DH;
            const u16* Vp = Vbase + (size_t)t * KB * DH;
            #pragma unroll
            for (int i = 0; i < KC; ++i) {
                int idx = tid + i * 128;
                *(u16x8*)&Ks[idx / DH8][(idx % DH8) * 8] =
                    *(const u16x8*)&Kp[(size_t)(idx / DH8) * DH + (idx % DH8) * 8];
            }
            #pragma unroll
            for (int u = 0; u < VU; ++u) {
                int uu = tid + u * 128;
                int d0 = (uu % DH8) * 8, s0 = (uu / DH8) * 4;
                u16x8 v0 = *(const u16x8*)&Vp[(size_t)(s0 + 0) * DH + d0];
                u16x8 v1 = *(const u16x8*)&Vp[(size_t)(s0 + 1) * DH + d0];
                u16x8 v2 = *(const u16x8*)&Vp[(size_t)(s0 + 2) * DH + d0];
                u16x8 v3 = *(const u16x8*)&Vp[(size_t)(s0 + 3) * DH + d0];
                #pragma unroll
                for (int j = 0; j < 8; ++j) {
                    u16x4 wj = {v0[j], v1[j], v2[j], v3[j]};
                    *(u16x4*)&Vt[d0 + j][s0] = wj;
                }
            }
        }
        __syncthreads();

        if (PRE && t + 1 < NT) {
            const u16* Kp = Kbase + (size_t)(t + 1) * KB * DH;
            const u16* Vp = Vbase + (size_t)(t + 1) * KB * DH;
            #pragma unroll
            for (int i = 0; i < KC; ++i) {
                int idx = tid + i * 128;
                kreg[i] = *(const u16x8*)&Kp[(size_t)(idx / DH8) * DH + (idx % DH8) * 8];
            }
            #pragma unroll
            for (int u = 0; u < VU; ++u) {
                int uu = tid + u * 128;
                int d0 = (uu % DH8) * 8, s0 = (uu / DH8) * 4;
                #pragma unroll
                for (int si = 0; si < 4; ++si)
                    vreg[u][si] = *(const u16x8*)&Vp[(size_t)(s0 + si) * DH + d0];
            }
        }

        f32x4 sacc[4][NQS];
        #pragma unroll
        for (int st = 0; st < 4; ++st)
            #pragma unroll
            for (int qs = 0; qs < NQS; ++qs)
                #pragma unroll
                for (int r = 0; r < 4; ++r) sacc[st][qs][r] = 0.f;
        #pragma unroll
        for (int st = 0; st < 4; ++st) {
            #pragma unroll
            for (int kk = 0; kk < NKK; ++kk) {
                short8 a = *(const short8*)&Ks[st * 16 + lo][kk * 32 + hi * 8];
                #pragma unroll
                for (int qs = 0; qs < NQS; ++qs)
                    sacc[st][qs] = __builtin_amdgcn_mfma_f32_16x16x32_bf16(
                        a, qf[qs][kk], sacc[st][qs], 0, 0, 0);
            }
        }

        #pragma unroll
        for (int qs = 0; qs < NQS; ++qs) {
            float tm = -1e30f;
            #pragma unroll
            for (int st = 0; st < 4; ++st)
                #pragma unroll
                for (int r = 0; r < 4; ++r) tm = fmaxf(tm, sacc[st][qs][r]);
            tm = fmaxf(tm, __shfl_xor(tm, 16));
            tm = fmaxf(tm, __shfl_xor(tm, 32));
            float mn = fmaxf(m_i[qs], tm);
            float alpha = __builtin_amdgcn_exp2f(m_i[qs] - mn);
            m_i[qs] = mn;
            float ts = 0.f;
            #pragma unroll
            for (int st = 0; st < 4; ++st) {
                float p0 = __builtin_amdgcn_exp2f(sacc[st][qs][0] - mn);
                float p1 = __builtin_amdgcn_exp2f(sacc[st][qs][1] - mn);
                float p2 = __builtin_amdgcn_exp2f(sacc[st][qs][2] - mn);
                float p3 = __builtin_amdgcn_exp2f(sacc[st][qs][3] - mn);
                ts += (p0 + p1) + (p2 + p3);
                u16x4 wp = {f2bf(p0), f2bf(p1), f2bf(p2), f2bf(p3)};
                *(u16x4*)&Ps[wv][qs * 16 + lo][st * 16 + hi * 4] = wp;
            }
            ts += __shfl_xor(ts, 16);
            ts += __shfl_xor(ts, 32);
            l_i[qs] = l_i[qs] * alpha + ts;
            float ar[4];
            #pragma unroll
            for (int r = 0; r < 4; ++r) ar[r] = __shfl(alpha, hi * 4 + r);
            #pragma unroll
            for (int nt = 0; nt < NNT; ++nt)
                #pragma unroll
                for (int r = 0; r < 4; ++r) acc[qs][nt][r] *= ar[r];
        }

        #pragma unroll
        for (int ks = 0; ks < 2; ++ks) {
            short8 pa[NQS];
            #pragma unroll
            for (int qs = 0; qs < NQS; ++qs)
                pa[qs] = *(const short8*)&Ps[wv][qs * 16 + lo][ks * 32 + hi * 8];
            #pragma unroll
            for (int nt = 0; nt < NNT; ++nt) {
                short8 vb = *(const short8*)&Vt[nt * 16 + lo][ks * 32 + hi * 8];
                #pragma unroll
                for (int qs = 0; qs < NQS; ++qs)
                    acc[qs][nt] = __builtin_amdgcn_mfma_f32_16x16x32_bf16(
                        pa[qs], vb, acc[qs][nt], 0, 0, 0);
            }
        }
    }

    const int b_ = bh / NHEADS, h_ = bh % NHEADS;
    #pragma unroll
    for (int qs = 0; qs < NQS; ++qs) {
        float inv = 1.0f / l_i[qs];
        float ir[4];
        #pragma unroll
        for (int r = 0; r < 4; ++r) ir[r] = __shfl(inv, hi * 4 + r);
        #pragma unroll
        for (int nt = 0; nt < NNT; ++nt)
            #pragma unroll
            for (int r = 0; r < 4; ++r) {
                int l = q0 + qs * 16 + hi * 4 + r;
                O[(((size_t)b_ * L + l) * NHEADS + h_) * DH + nt * 16 + lo] =
                    f2bf(acc[qs][nt][r] * ir[r]);
            }
    }
}

// ---------------------------------------------------------------------------

static void run_flash(int dh, const u16* Q, const u16* K, const u16* V,
                      u16* O, int L, hipStream_t stream)
{
    const int BH = 2 * NHEADS;
    if (dh == 64)
        flash_split<64><<<BH * (L / 64), 256, 0, stream>>>(Q, K, V, O, L, L);
    else if (dh == 128)
        flash_mfma<128, 2, 1><<<BH * (L / 64), 128, 0, stream>>>(Q, K, V, O, L, L);
    else
        flash_mfma<256, 1, 0><<<BH * (L / 32), 128, 0, stream>>>(Q, K, V, O, L, L);
}

extern "C" void kernel_launch(void* const* d_in, const int* in_sizes, int n_in,
                              void* d_out, int out_size, void* d_ws, size_t ws_size,
                              hipStream_t stream)
{
    static const int CHs[4] = {64, 128, 256, 512};
    static const int HWs[4] = {128, 64, 32, 16};

    const float* f1[4] = {(const float*)d_in[0], (const float*)d_in[1],
                          (const float*)d_in[2], (const float*)d_in[3]};
    const float* f2[4] = {nullptr, (const float*)d_in[4], (const float*)d_in[6],
                          (const float*)d_in[8]};
    const float* f3[4] = {nullptr, (const float*)d_in[5], (const float*)d_in[7],
                          (const float*)d_in[9]};

    // level 0: pass-through
    size_t out0_elems = (size_t)in_sizes[0];
    hipMemcpyAsync(d_out, d_in[0], out0_elems * sizeof(float),
                   hipMemcpyDeviceToDevice, stream);

    // workspace: 9 bf16 slots of 2*4096*128 elems (18 MB total)
    const size_t SL = (size_t)2 * 4096 * 128;
    u16* wsu = (u16*)d_ws;
    u16* f1t = wsu + 0 * SL;
    u16* f2t = wsu + 1 * SL;
    u16* f3t = wsu + 2 * SL;
    u16* Qb  = wsu + 3 * SL;
    u16* Kb  = wsu + 4 * SL;
    u16* Vb  = wsu + 5 * SL;
    u16* An  = wsu + 6 * SL;
    u16* A1t = wsu + 7 * SL;
    u16* A2t = wsu + 8 * SL;

    const float LOG2E = 1.44269504088896340736f;

    size_t outOff = out0_elems;
    for (int lvl = 1; lvl <= 3; ++lvl) {
        const int C = CHs[lvl];
        const int Hs = HWs[lvl];
        const int L = Hs * Hs;
        const int dh = C / NHEADS;
        const int M = 2 * L;  // B*L
        const float qscale = LOG2E / sqrtf((float)dh);
        const int bi = 10 + (lvl - 1) * 10;
        const float* a12w  = (const float*)d_in[bi + 0];
        const float* a12b  = (const float*)d_in[bi + 1];
        const float* a12ow = (const float*)d_in[bi + 2];
        const float* a12ob = (const float*)d_in[bi + 3];
        const float* a13w  = (const float*)d_in[bi + 4];
        const float* a13b  = (const float*)d_in[bi + 5];
        const float* a13ow = (const float*)d_in[bi + 6];
        const float* a13ob = (const float*)d_in[bi + 7];
        const float* sqw   = (const float*)d_in[bi + 8];
        const float* sqb   = (const float*)d_in[bi + 9];

        // transpose f1/f2/f3 -> bf16 [b, l, c]
        dim3 tg(L / 32, C / 32, 6);
        transpose_bf16_kernel<<<tg, 256, 0, stream>>>(f1[lvl], f2[lvl], f3[lvl],
                                                      f1t, f2t, f3t, C, L);

        dim3 gq(3 * C / 64, M / 64);
        dim3 gp(C / 64, M / 64);

        // attention 1: Q from f1t, K/V from f2t
        gemm_bf16<0><<<gq, 256, 0, stream>>>(f1t, f2t, nullptr, a12w, a12b,
                                             (void*)Qb, Kb, Vb,
                                             M, 3 * C, C, C, L, dh, qscale);
        run_flash(dh, Qb, Kb, Vb, An, L, stream);
        gemm_bf16<1><<<gp, 256, 0, stream>>>(An, nullptr, nullptr, a12ow, a12ob,
                                             (void*)A1t, nullptr, nullptr,
                                             M, C, C, C, L, dh, 1.0f);

        // attention 2: Q from f1t, K/V from f3t
        gemm_bf16<0><<<gq, 256, 0, stream>>>(f1t, f3t, nullptr, a13w, a13b,
                                             (void*)Qb, Kb, Vb,
                                             M, 3 * C, C, C, L, dh, qscale);
        run_flash(dh, Qb, Kb, Vb, An, L, stream);
        gemm_bf16<1><<<gp, 256, 0, stream>>>(An, nullptr, nullptr, a13ow, a13ob,
                                             (void*)A2t, nullptr, nullptr,
                                             M, C, C, C, L, dh, 1.0f);

        // squeeze into d_out (fp32 [b, n, l])
        gemm_bf16<2><<<gp, 256, 0, stream>>>(f1t, A1t, A2t, sqw, sqb,
                                             (void*)((float*)d_out + outOff),
                                             nullptr, nullptr,
                                             M, C, 3 * C, C, L, dh, 1.0f);
        outOff += (size_t)2 * C * L;
    }
}

// Round 5
// 380.553 us; speedup vs baseline: 7.7110x; 1.1929x over previous
//
#include <hip/hip_runtime.h>
#include <hip/hip_bf16.h>
#include <math.h>

#define NHEADS 2

typedef unsigned short u16;
typedef __attribute__((ext_vector_type(8))) unsigned short u16x8;
typedef __attribute__((ext_vector_type(4))) unsigned short u16x4;
typedef __attribute__((ext_vector_type(8))) short short8;
typedef __attribute__((ext_vector_type(4))) float f32x4;

__device__ __forceinline__ u16 f2bf(float x) {
    __hip_bfloat16 h = __float2bfloat16(x);
    return __builtin_bit_cast(unsigned short, h);
}

// ---------------------------------------------------------------------------
// Transpose + bf16 convert: f [b, c, l] fp32  ->  ft [b, l, c] bf16.
// ---------------------------------------------------------------------------
__global__ __launch_bounds__(256) void transpose_bf16_kernel(
    const float* __restrict__ s0, const float* __restrict__ s1,
    const float* __restrict__ s2,
    u16* __restrict__ d0, u16* __restrict__ d1, u16* __restrict__ d2,
    int C, int L)
{
    const int z = blockIdx.z;
    const int which = z >> 1;
    const int b = z & 1;
    const float* __restrict__ src = (which == 0) ? s0 : (which == 1 ? s1 : s2);
    u16* __restrict__ dst = (which == 0) ? d0 : (which == 1 ? d1 : d2);
    const int l0 = blockIdx.x * 32;
    const int c0 = blockIdx.y * 32;
    __shared__ float Ts[32][33];
    const int t = threadIdx.x;
    const int x = t & 31, y = t >> 5;
    #pragma unroll
    for (int p = 0; p < 4; ++p)
        Ts[y + 8 * p][x] = src[((size_t)(b * C + c0 + y + 8 * p)) * L + l0 + x];
    __syncthreads();
    #pragma unroll
    for (int p = 0; p < 4; ++p)
        dst[((size_t)(b * L + l0 + y + 8 * p)) * C + c0 + x] = f2bf(Ts[x][y + 8 * p]);
}

// ---------------------------------------------------------------------------
// bf16 MFMA GEMM: out[n,m] = sum_k W[n,k]*X[m,k] + bias[n]
// ---------------------------------------------------------------------------
template <int MODE>
__global__ __launch_bounds__(256) void gemm_bf16(
    const u16* __restrict__ X0, const u16* __restrict__ X1,
    const u16* __restrict__ X2,
    const float* __restrict__ W, const float* __restrict__ bias,
    void* __restrict__ out0, u16* __restrict__ out1, u16* __restrict__ out2,
    int M, int N, int K, int C, int L, int dh, float qscale)
{
    const int n0 = blockIdx.x * 64;
    const int m0 = blockIdx.y * 64;
    __shared__ __align__(16) u16 Xs[64][72];
    __shared__ __align__(16) u16 Ws[64][72];
    const int tid = threadIdx.x;
    const int wid = tid >> 6, lane = tid & 63;
    const int lo = lane & 15, hi = lane >> 4;
    const int wm = wid >> 1, wn = wid & 1;
    const int Kx = (MODE == 2) ? C : K;

    const u16* __restrict__ Xbase = (MODE == 0) ? ((n0 < C) ? X0 : X1) : X0;

    f32x4 acc[2][2];
    #pragma unroll
    for (int i = 0; i < 2; ++i)
        #pragma unroll
        for (int j = 0; j < 2; ++j)
            #pragma unroll
            for (int r = 0; r < 4; ++r) acc[i][j][r] = 0.f;

    u16x8 xreg[2];
    f32x4 wreg[4];

    auto load_x = [&](int k0) {
        const u16* src; int kl;
        if (MODE == 2) {
            int wk = k0 / C;
            src = (wk == 0) ? X0 : (wk == 1 ? X1 : X2);
            kl = k0 - wk * C;
        } else { src = Xbase; kl = k0; }
        #pragma unroll
        for (int p = 0; p < 2; ++p) {
            int c = tid + p * 256;
            int row = c >> 3, kc = c & 7;
            xreg[p] = *(const u16x8*)&src[(size_t)(m0 + row) * Kx + kl + kc * 8];
        }
    };
    auto load_w = [&](int k0) {
        #pragma unroll
        for (int p = 0; p < 4; ++p) {
            int c = tid + p * 256;
            int row = c >> 4, kc = c & 15;
            wreg[p] = *(const f32x4*)&W[(size_t)(n0 + row) * K + k0 + kc * 4];
        }
    };

    load_x(0);
    load_w(0);
    const int ns = K / 64;
    for (int s = 0; s < ns; ++s) {
        __syncthreads();
        #pragma unroll
        for (int p = 0; p < 2; ++p) {
            int c = tid + p * 256;
            int row = c >> 3, kc = c & 7;
            *(u16x8*)&Xs[row][kc * 8] = xreg[p];
        }
        #pragma unroll
        for (int p = 0; p < 4; ++p) {
            int c = tid + p * 256;
            int row = c >> 4, kc = c & 15;
            u16x4 cv = {f2bf(wreg[p][0]), f2bf(wreg[p][1]),
                        f2bf(wreg[p][2]), f2bf(wreg[p][3])};
            *(u16x4*)&Ws[row][kc * 4] = cv;
        }
        __syncthreads();
        if (s + 1 < ns) { load_x((s + 1) * 64); load_w((s + 1) * 64); }
        #pragma unroll
        for (int kk = 0; kk < 2; ++kk) {
            short8 wf0 = *(const short8*)&Ws[wn * 32 + lo][kk * 32 + hi * 8];
            short8 wf1 = *(const short8*)&Ws[wn * 32 + 16 + lo][kk * 32 + hi * 8];
            short8 xf0 = *(const short8*)&Xs[wm * 32 + lo][kk * 32 + hi * 8];
            short8 xf1 = *(const short8*)&Xs[wm * 32 + 16 + lo][kk * 32 + hi * 8];
            acc[0][0] = __builtin_amdgcn_mfma_f32_16x16x32_bf16(wf0, xf0, acc[0][0], 0, 0, 0);
            acc[0][1] = __builtin_amdgcn_mfma_f32_16x16x32_bf16(wf1, xf0, acc[0][1], 0, 0, 0);
            acc[1][0] = __builtin_amdgcn_mfma_f32_16x16x32_bf16(wf0, xf1, acc[1][0], 0, 0, 0);
            acc[1][1] = __builtin_amdgcn_mfma_f32_16x16x32_bf16(wf1, xf1, acc[1][1], 0, 0, 0);
        }
    }

    #pragma unroll
    for (int nt = 0; nt < 2; ++nt) {
        const int nb = n0 + wn * 32 + nt * 16 + hi * 4;
        const float b0 = bias[nb + 0], b1 = bias[nb + 1];
        const float b2 = bias[nb + 2], b3 = bias[nb + 3];
        if (MODE == 0) {
            const int which = nb / C;
            const int co = nb - which * C;
            const int h = co / dh;
            const int dd = co - h * dh;
            u16* dst = (which == 0) ? (u16*)out0 : (which == 1 ? out1 : out2);
            const float sc = (which == 0) ? qscale : 1.0f;
            #pragma unroll
            for (int mt = 0; mt < 2; ++mt) {
                int m = m0 + wm * 32 + mt * 16 + lo;
                int b_ = m / L; int l = m - b_ * L;
                u16x4 pk = {f2bf((acc[mt][nt][0] + b0) * sc),
                            f2bf((acc[mt][nt][1] + b1) * sc),
                            f2bf((acc[mt][nt][2] + b2) * sc),
                            f2bf((acc[mt][nt][3] + b3) * sc)};
                *(u16x4*)&dst[((size_t)(b_ * NHEADS + h) * L + l) * dh + dd] = pk;
            }
        } else if (MODE == 1) {
            u16* dst = (u16*)out0;
            #pragma unroll
            for (int mt = 0; mt < 2; ++mt) {
                int m = m0 + wm * 32 + mt * 16 + lo;
                u16x4 pk = {f2bf(acc[mt][nt][0] + b0), f2bf(acc[mt][nt][1] + b1),
                            f2bf(acc[mt][nt][2] + b2), f2bf(acc[mt][nt][3] + b3)};
                *(u16x4*)&dst[(size_t)m * N + nb] = pk;
            }
        } else {
            float* dst = (float*)out0;
            #pragma unroll
            for (int mt = 0; mt < 2; ++mt) {
                int m = m0 + wm * 32 + mt * 16 + lo;
                int b_ = m / L; int l = m - b_ * L;
                dst[((size_t)(b_ * C + nb + 0)) * L + l] = acc[mt][nt][0] + b0;
                dst[((size_t)(b_ * C + nb + 1)) * L + l] = acc[mt][nt][1] + b1;
                dst[((size_t)(b_ * C + nb + 2)) * L + l] = acc[mt][nt][2] + b2;
                dst[((size_t)(b_ * C + nb + 3)) * L + l] = acc[mt][nt][3] + b3;
            }
        }
    }
}

// ---------------------------------------------------------------------------
// Level-1 flash: 512 threads = 8 waves = 2 q-groups x 4 s-parities.
// Single-buffered 4-tile rounds (2 barriers/round), register prefetch (T14),
// XOR-swizzled V^T LDS, defer-max (T13, THR=8 log2), 4-way fp32 merge
// epilogue aliased into the K/V LDS region. DH=64, KB=64.
// ---------------------------------------------------------------------------
template <int DH>
__global__ __launch_bounds__(512) void flash_split8(
    const u16* __restrict__ Q, const u16* __restrict__ K,
    const u16* __restrict__ V, u16* __restrict__ O, int L, int S)
{
    constexpr int KB = 64;
    constexpr int NQS = 2;
    constexpr int QW = 32;
    constexpr int QB = 64;
    constexpr int NKK = DH / 32;   // 2
    constexpr int NNT = DH / 16;   // 4
    constexpr int NPAR = 4;
    constexpr int KPAD = DH + 8;   // 72
    constexpr int SZ_KS = NPAR * KB * KPAD * 2;     // 36864
    constexpr int SZ_VT = NPAR * DH * KB * 2;       // 32768
    constexpr int SZ_PS = 8 * QW * (KB + 8) * 2;    // 36864

    __shared__ __align__(16) char smem[SZ_KS + SZ_VT + SZ_PS];
    u16 (*Ks)[KB][KPAD]  = (u16 (*)[KB][KPAD])(smem);
    u16 (*Vt)[DH][KB]    = (u16 (*)[DH][KB])(smem + SZ_KS);
    u16 (*Ps)[QW][KB + 8] = (u16 (*)[QW][KB + 8])(smem + SZ_KS + SZ_VT);
    float* MrgAcc = (float*)smem;                    // [2][3][QW][DH]
    float* MrgML  = (float*)(smem + 2 * 3 * QW * DH * 4);  // [2][3][2][QW]

    const int nQT = L / QB;
    const int qt = blockIdx.x % nQT;
    const int bh = blockIdx.x / nQT;
    const int tid = threadIdx.x;
    const int w = tid >> 6;
    const int lane = tid & 63;
    const int lo = lane & 15, hi = lane >> 4;
    const int qg = w & 1, par = w >> 1;
    const int q0 = qt * QB + qg * QW;

    // ---- Q fragments in registers
    short8 qf[NQS][NKK];
    #pragma unroll
    for (int qs = 0; qs < NQS; ++qs)
        #pragma unroll
        for (int kk = 0; kk < NKK; ++kk)
            qf[qs][kk] = *(const short8*)&Q[((size_t)bh * L + q0 + qs * 16 + lo) * DH + kk * 32 + hi * 8];

    f32x4 acc[NQS][NNT];
    #pragma unroll
    for (int qs = 0; qs < NQS; ++qs)
        #pragma unroll
        for (int nt = 0; nt < NNT; ++nt)
            #pragma unroll
            for (int r = 0; r < 4; ++r) acc[qs][nt][r] = 0.f;
    float m_i[NQS], l_i[NQS];
    #pragma unroll
    for (int qs = 0; qs < NQS; ++qs) { m_i[qs] = -1e30f; l_i[qs] = 0.f; }

    const u16* Kbase = K + (size_t)bh * S * DH;
    const u16* Vbase = V + (size_t)bh * S * DH;

    // staging role: thread stages tile-slot pt of each round
    const int pt = tid >> 7;                          // 0..3
    const int u = tid & 127;
    const int sK = u >> 1, dKo = (u & 1) * 32;        // K: 4x16B along row sK
    const int dV0 = (u & 7) * 8, sV0 = (u >> 3) * 4;  // V: 4 rows x 8 d

    u16x8 kreg[4], vreg[4];

    auto loadround = [&](int r) {
        const u16* Kp = Kbase + (size_t)(NPAR * r + pt) * KB * DH;
        const u16* Vp = Vbase + (size_t)(NPAR * r + pt) * KB * DH;
        #pragma unroll
        for (int c = 0; c < 4; ++c)
            kreg[c] = *(const u16x8*)&Kp[(size_t)sK * DH + dKo + 8 * c];
        #pragma unroll
        for (int si = 0; si < 4; ++si)
            vreg[si] = *(const u16x8*)&Vp[(size_t)(sV0 + si) * DH + dV0];
    };
    auto writeround = [&]() {
        #pragma unroll
        for (int c = 0; c < 4; ++c)
            *(u16x8*)&Ks[pt][sK][dKo + 8 * c] = kreg[c];
        #pragma unroll
        for (int j = 0; j < 8; ++j) {
            int d = dV0 + j;
            int g = ((d >> 3) ^ d) & 7;
            int scol = (sV0 & 7) | ((((sV0 >> 3) ^ g) & 7) << 3);
            u16x4 wj = {vreg[0][j], vreg[1][j], vreg[2][j], vreg[3][j]};
            *(u16x4*)&Vt[pt][d][scol] = wj;
        }
    };

    const int NR = S / (KB * NPAR);

    loadround(0);
    writeround();
    __syncthreads();

    for (int r = 0; r < NR; ++r) {
        if (r + 1 < NR) loadround(r + 1);

        // ---- QK^T (swapped) from Ks[par]
        f32x4 sacc[4][NQS];
        #pragma unroll
        for (int st = 0; st < 4; ++st)
            #pragma unroll
            for (int qs = 0; qs < NQS; ++qs)
                #pragma unroll
                for (int rr = 0; rr < 4; ++rr) sacc[st][qs][rr] = 0.f;
        #pragma unroll
        for (int st = 0; st < 4; ++st) {
            #pragma unroll
            for (int kk = 0; kk < NKK; ++kk) {
                short8 a = *(const short8*)&Ks[par][st * 16 + lo][kk * 32 + hi * 8];
                #pragma unroll
                for (int qs = 0; qs < NQS; ++qs)
                    sacc[st][qs] = __builtin_amdgcn_mfma_f32_16x16x32_bf16(
                        a, qf[qs][kk], sacc[st][qs], 0, 0, 0);
            }
        }

        // ---- online softmax (log2 domain) with defer-max, P -> LDS bf16
        #pragma unroll
        for (int qs = 0; qs < NQS; ++qs) {
            float tm = -1e30f;
            #pragma unroll
            for (int st = 0; st < 4; ++st)
                #pragma unroll
                for (int rr = 0; rr < 4; ++rr) tm = fmaxf(tm, sacc[st][qs][rr]);
            tm = fmaxf(tm, __shfl_xor(tm, 16));
            tm = fmaxf(tm, __shfl_xor(tm, 32));
            const bool grow = __any(tm > m_i[qs] + 8.0f);
            const float mn = grow ? fmaxf(m_i[qs], tm) : m_i[qs];
            float ts = 0.f;
            #pragma unroll
            for (int st = 0; st < 4; ++st) {
                float p0 = __builtin_amdgcn_exp2f(sacc[st][qs][0] - mn);
                float p1 = __builtin_amdgcn_exp2f(sacc[st][qs][1] - mn);
                float p2 = __builtin_amdgcn_exp2f(sacc[st][qs][2] - mn);
                float p3 = __builtin_amdgcn_exp2f(sacc[st][qs][3] - mn);
                ts += (p0 + p1) + (p2 + p3);
                u16x4 wp = {f2bf(p0), f2bf(p1), f2bf(p2), f2bf(p3)};
                *(u16x4*)&Ps[w][qs * 16 + lo][st * 16 + hi * 4] = wp;
            }
            ts += __shfl_xor(ts, 16);
            ts += __shfl_xor(ts, 32);
            if (grow) {
                float alpha = __builtin_amdgcn_exp2f(m_i[qs] - mn);
                m_i[qs] = mn;
                l_i[qs] = l_i[qs] * alpha + ts;
                float ar[4];
                #pragma unroll
                for (int rr = 0; rr < 4; ++rr) ar[rr] = __shfl(alpha, hi * 4 + rr);
                #pragma unroll
                for (int nt = 0; nt < NNT; ++nt)
                    #pragma unroll
                    for (int rr = 0; rr < 4; ++rr) acc[qs][nt][rr] *= ar[rr];
            } else {
                l_i[qs] += ts;
            }
        }

        // ---- PV from swizzled Vt[par]
        #pragma unroll
        for (int ks = 0; ks < 2; ++ks) {
            short8 pa[NQS];
            #pragma unroll
            for (int qs = 0; qs < NQS; ++qs)
                pa[qs] = *(const short8*)&Ps[w][qs * 16 + lo][ks * 32 + hi * 8];
            #pragma unroll
            for (int nt = 0; nt < NNT; ++nt) {
                int d = nt * 16 + lo;
                int g = ((d >> 3) ^ d) & 7;
                int scol = (((4 * ks + hi) ^ g) & 7) << 3;
                short8 vb = *(const short8*)&Vt[par][d][scol];
                #pragma unroll
                for (int qs = 0; qs < NQS; ++qs)
                    acc[qs][nt] = __builtin_amdgcn_mfma_f32_16x16x32_bf16(
                        pa[qs], vb, acc[qs][nt], 0, 0, 0);
            }
        }

        __syncthreads();               // all waves done reading round r
        if (r + 1 < NR) writeround();  // vmcnt-waits on prefetched regs
        __syncthreads();               // round r+1 visible
    }

    // ---- 4-way merge epilogue (MrgAcc/MrgML alias the Ks/Vt region)
    if (par != 0) {
        float* ma = MrgAcc + (size_t)(qg * 3 + par - 1) * QW * DH;
        #pragma unroll
        for (int qs = 0; qs < NQS; ++qs) {
            #pragma unroll
            for (int nt = 0; nt < NNT; ++nt)
                #pragma unroll
                for (int rr = 0; rr < 4; ++rr)
                    ma[(size_t)(qs * 16 + hi * 4 + rr) * DH + nt * 16 + lo] = acc[qs][nt][rr];
            if (hi == 0) {
                MrgML[((qg * 3 + par - 1) * 2 + 0) * QW + qs * 16 + lo] = m_i[qs];
                MrgML[((qg * 3 + par - 1) * 2 + 1) * QW + qs * 16 + lo] = l_i[qs];
            }
        }
    }
    __syncthreads();
    if (par == 0) {
        const int b_ = bh / NHEADS, h_ = bh % NHEADS;
        #pragma unroll
        for (int qs = 0; qs < NQS; ++qs) {
            float mp[3], lp[3];
            #pragma unroll
            for (int p = 0; p < 3; ++p) {
                mp[p] = MrgML[((qg * 3 + p) * 2 + 0) * QW + qs * 16 + lo];
                lp[p] = MrgML[((qg * 3 + p) * 2 + 1) * QW + qs * 16 + lo];
            }
            float mt = fmaxf(fmaxf(m_i[qs], mp[0]), fmaxf(mp[1], mp[2]));
            float c0 = __builtin_amdgcn_exp2f(m_i[qs] - mt);
            float lt = c0 * l_i[qs];
            float cp[3];
            #pragma unroll
            for (int p = 0; p < 3; ++p) {
                cp[p] = __builtin_amdgcn_exp2f(mp[p] - mt);
                lt += cp[p] * lp[p];
            }
            float linv = 1.0f / lt;
            c0 *= linv;
            #pragma unroll
            for (int p = 0; p < 3; ++p) cp[p] *= linv;
            float c0r[4], cpr[3][4];
            #pragma unroll
            for (int rr = 0; rr < 4; ++rr) {
                c0r[rr] = __shfl(c0, hi * 4 + rr);
                #pragma unroll
                for (int p = 0; p < 3; ++p) cpr[p][rr] = __shfl(cp[p], hi * 4 + rr);
            }
            #pragma unroll
            for (int nt = 0; nt < NNT; ++nt)
                #pragma unroll
                for (int rr = 0; rr < 4; ++rr) {
                    int q = qs * 16 + hi * 4 + rr;
                    float ov = acc[qs][nt][rr] * c0r[rr];
                    #pragma unroll
                    for (int p = 0; p < 3; ++p)
                        ov += MrgAcc[((size_t)(qg * 3 + p) * QW + q) * DH + nt * 16 + lo] * cpr[p][rr];
                    O[(((size_t)b_ * L + q0 + q) * NHEADS + h_) * DH + nt * 16 + lo] = f2bf(ov);
                }
        }
    }
}

// ---------------------------------------------------------------------------
// Levels 2/3 flash: 128 threads, 2 waves, defer-max added.
// ---------------------------------------------------------------------------
template <int DH, int NQS, int PRE>
__global__ __launch_bounds__(128) void flash_mfma(
    const u16* __restrict__ Q, const u16* __restrict__ K,
    const u16* __restrict__ V, u16* __restrict__ O, int L, int S)
{
    constexpr int KB = 64;
    constexpr int QW = NQS * 16;
    constexpr int QB = 2 * QW;
    constexpr int DH8 = DH / 8;
    constexpr int KC = (KB * DH8) / 128;
    constexpr int VU = (16 * DH8) / 128;
    constexpr int NKK = DH / 32;
    constexpr int NNT = DH / 16;
    constexpr int PADS = KB + 8;

    __shared__ __align__(16) u16 Ks[KB][DH + 8];
    __shared__ __align__(16) u16 Vt[DH][PADS];
    __shared__ __align__(16) u16 Ps[2][QW][PADS];

    const int nQT = L / QB;
    const int qt = blockIdx.x % nQT;
    const int bh = blockIdx.x / nQT;
    const int tid = threadIdx.x;
    const int wv = tid >> 6;
    const int lane = tid & 63;
    const int lo = lane & 15;
    const int hi = lane >> 4;
    const int q0 = qt * QB + wv * QW;

    short8 qf[NQS][NKK];
    #pragma unroll
    for (int qs = 0; qs < NQS; ++qs)
        #pragma unroll
        for (int kk = 0; kk < NKK; ++kk)
            qf[qs][kk] = *(const short8*)&Q[((size_t)bh * L + q0 + qs * 16 + lo) * DH + kk * 32 + hi * 8];

    f32x4 acc[NQS][NNT];
    #pragma unroll
    for (int qs = 0; qs < NQS; ++qs)
        #pragma unroll
        for (int nt = 0; nt < NNT; ++nt)
            #pragma unroll
            for (int r = 0; r < 4; ++r) acc[qs][nt][r] = 0.f;
    float m_i[NQS], l_i[NQS];
    #pragma unroll
    for (int qs = 0; qs < NQS; ++qs) { m_i[qs] = -1e30f; l_i[qs] = 0.f; }

    const int NT = S / KB;
    u16x8 kreg[PRE ? KC : 1];
    u16x8 vreg[PRE ? VU : 1][4];

    const u16* Kbase = K + (size_t)bh * S * DH;
    const u16* Vbase = V + (size_t)bh * S * DH;

    if (PRE) {
        #pragma unroll
        for (int i = 0; i < KC; ++i) {
            int idx = tid + i * 128;
            kreg[i] = *(const u16x8*)&Kbase[(size_t)(idx / DH8) * DH + (idx % DH8) * 8];
        }
        #pragma unroll
        for (int u = 0; u < VU; ++u) {
            int uu = tid + u * 128;
            int d0 = (uu % DH8) * 8, s0 = (uu / DH8) * 4;
            #pragma unroll
            for (int si = 0; si < 4; ++si)
                vreg[u][si] = *(const u16x8*)&Vbase[(size_t)(s0 + si) * DH + d0];
        }
    }

    for (int t = 0; t < NT; ++t) {
        __syncthreads();
        if (PRE) {
            #pragma unroll
            for (int i = 0; i < KC; ++i) {
                int idx = tid + i * 128;
                *(u16x8*)&Ks[idx / DH8][(idx % DH8) * 8] = kreg[i];
            }
            #pragma unroll
            for (int u = 0; u < VU; ++u) {
                int uu = tid + u * 128;
                int d0 = (uu % DH8) * 8, s0 = (uu / DH8) * 4;
                #pragma unroll
                for (int j = 0; j < 8; ++j) {
                    u16x4 wj = {vreg[u][0][j], vreg[u][1][j], vreg[u][2][j], vreg[u][3][j]};
                    *(u16x4*)&Vt[d0 + j][s0] = wj;
                }
            }
        } else {
            const u16* Kp = Kbase + (size_t)t * KB * DH;
            const u16* Vp = Vbase + (size_t)t * KB * DH;
            #pragma unroll
            for (int i = 0; i < KC; ++i) {
                int idx = tid + i * 128;
                *(u16x8*)&Ks[idx / DH8][(idx % DH8) * 8] =
                    *(const u16x8*)&Kp[(size_t)(idx / DH8) * DH + (idx % DH8) * 8];
            }
            #pragma unroll
            for (int u = 0; u < VU; ++u) {
                int uu = tid + u * 128;
                int d0 = (uu % DH8) * 8, s0 = (uu / DH8) * 4;
                u16x8 v0 = *(const u16x8*)&Vp[(size_t)(s0 + 0) * DH + d0];
                u16x8 v1 = *(const u16x8*)&Vp[(size_t)(s0 + 1) * DH + d0];
                u16x8 v2 = *(const u16x8*)&Vp[(size_t)(s0 + 2) * DH + d0];
                u16x8 v3 = *(const u16x8*)&Vp[(size_t)(s0 + 3) * DH + d0];
                #pragma unroll
                for (int j = 0; j < 8; ++j) {
                    u16x4 wj = {v0[j], v1[j], v2[j], v3[j]};
                    *(u16x4*)&Vt[d0 + j][s0] = wj;
                }
            }
        }
        __syncthreads();

        if (PRE && t + 1 < NT) {
            const u16* Kp = Kbase + (size_t)(t + 1) * KB * DH;
            const u16* Vp = Vbase + (size_t)(t + 1) * KB * DH;
            #pragma unroll
            for (int i = 0; i < KC; ++i) {
                int idx = tid + i * 128;
                kreg[i] = *(const u16x8*)&Kp[(size_t)(idx / DH8) * DH + (idx % DH8) * 8];
            }
            #pragma unroll
            for (int u = 0; u < VU; ++u) {
                int uu = tid + u * 128;
                int d0 = (uu % DH8) * 8, s0 = (uu / DH8) * 4;
                #pragma unroll
                for (int si = 0; si < 4; ++si)
                    vreg[u][si] = *(const u16x8*)&Vp[(size_t)(s0 + si) * DH + d0];
            }
        }

        f32x4 sacc[4][NQS];
        #pragma unroll
        for (int st = 0; st < 4; ++st)
            #pragma unroll
            for (int qs = 0; qs < NQS; ++qs)
                #pragma unroll
                for (int r = 0; r < 4; ++r) sacc[st][qs][r] = 0.f;
        #pragma unroll
        for (int st = 0; st < 4; ++st) {
            #pragma unroll
            for (int kk = 0; kk < NKK; ++kk) {
                short8 a = *(const short8*)&Ks[st * 16 + lo][kk * 32 + hi * 8];
                #pragma unroll
                for (int qs = 0; qs < NQS; ++qs)
                    sacc[st][qs] = __builtin_amdgcn_mfma_f32_16x16x32_bf16(
                        a, qf[qs][kk], sacc[st][qs], 0, 0, 0);
            }
        }

        #pragma unroll
        for (int qs = 0; qs < NQS; ++qs) {
            float tm = -1e30f;
            #pragma unroll
            for (int st = 0; st < 4; ++st)
                #pragma unroll
                for (int r = 0; r < 4; ++r) tm = fmaxf(tm, sacc[st][qs][r]);
            tm = fmaxf(tm, __shfl_xor(tm, 16));
            tm = fmaxf(tm, __shfl_xor(tm, 32));
            const bool grow = __any(tm > m_i[qs] + 8.0f);
            const float mn = grow ? fmaxf(m_i[qs], tm) : m_i[qs];
            float ts = 0.f;
            #pragma unroll
            for (int st = 0; st < 4; ++st) {
                float p0 = __builtin_amdgcn_exp2f(sacc[st][qs][0] - mn);
                float p1 = __builtin_amdgcn_exp2f(sacc[st][qs][1] - mn);
                float p2 = __builtin_amdgcn_exp2f(sacc[st][qs][2] - mn);
                float p3 = __builtin_amdgcn_exp2f(sacc[st][qs][3] - mn);
                ts += (p0 + p1) + (p2 + p3);
                u16x4 wp = {f2bf(p0), f2bf(p1), f2bf(p2), f2bf(p3)};
                *(u16x4*)&Ps[wv][qs * 16 + lo][st * 16 + hi * 4] = wp;
            }
            ts += __shfl_xor(ts, 16);
            ts += __shfl_xor(ts, 32);
            if (grow) {
                float alpha = __builtin_amdgcn_exp2f(m_i[qs] - mn);
                m_i[qs] = mn;
                l_i[qs] = l_i[qs] * alpha + ts;
                float ar[4];
                #pragma unroll
                for (int r = 0; r < 4; ++r) ar[r] = __shfl(alpha, hi * 4 + r);
                #pragma unroll
                for (int nt = 0; nt < NNT; ++nt)
                    #pragma unroll
                    for (int r = 0; r < 4; ++r) acc[qs][nt][r] *= ar[r];
            } else {
                l_i[qs] += ts;
            }
        }

        #pragma unroll
        for (int ks = 0; ks < 2; ++ks) {
            short8 pa[NQS];
            #pragma unroll
            for (int qs = 0; qs < NQS; ++qs)
                pa[qs] = *(const short8*)&Ps[wv][qs * 16 + lo][ks * 32 + hi * 8];
            #pragma unroll
            for (int nt = 0; nt < NNT; ++nt) {
                short8 vb = *(const short8*)&Vt[nt * 16 + lo][ks * 32 + hi * 8];
                #pragma unroll
                for (int qs = 0; qs < NQS; ++qs)
                    acc[qs][nt] = __builtin_amdgcn_mfma_f32_16x16x32_bf16(
                        pa[qs], vb, acc[qs][nt], 0, 0, 0);
            }
        }
    }

    const int b_ = bh / NHEADS, h_ = bh % NHEADS;
    #pragma unroll
    for (int qs = 0; qs < NQS; ++qs) {
        float inv = 1.0f / l_i[qs];
        float ir[4];
        #pragma unroll
        for (int r = 0; r < 4; ++r) ir[r] = __shfl(inv, hi * 4 + r);
        #pragma unroll
        for (int nt = 0; nt < NNT; ++nt)
            #pragma unroll
            for (int r = 0; r < 4; ++r) {
                int l = q0 + qs * 16 + hi * 4 + r;
                O[(((size_t)b_ * L + l) * NHEADS + h_) * DH + nt * 16 + lo] =
                    f2bf(acc[qs][nt][r] * ir[r]);
            }
    }
}

// ---------------------------------------------------------------------------

static void run_flash(int dh, const u16* Q, const u16* K, const u16* V,
                      u16* O, int L, hipStream_t stream)
{
    const int BH = 2 * NHEADS;
    if (dh == 64)
        flash_split8<64><<<BH * (L / 64), 512, 0, stream>>>(Q, K, V, O, L, L);
    else if (dh == 128)
        flash_mfma<128, 1, 1><<<BH * (L / 32), 128, 0, stream>>>(Q, K, V, O, L, L);
    else
        flash_mfma<256, 1, 0><<<BH * (L / 32), 128, 0, stream>>>(Q, K, V, O, L, L);
}

extern "C" void kernel_launch(void* const* d_in, const int* in_sizes, int n_in,
                              void* d_out, int out_size, void* d_ws, size_t ws_size,
                              hipStream_t stream)
{
    static const int CHs[4] = {64, 128, 256, 512};
    static const int HWs[4] = {128, 64, 32, 16};

    const float* f1[4] = {(const float*)d_in[0], (const float*)d_in[1],
                          (const float*)d_in[2], (const float*)d_in[3]};
    const float* f2[4] = {nullptr, (const float*)d_in[4], (const float*)d_in[6],
                          (const float*)d_in[8]};
    const float* f3[4] = {nullptr, (const float*)d_in[5], (const float*)d_in[7],
                          (const float*)d_in[9]};

    // level 0: pass-through
    size_t out0_elems = (size_t)in_sizes[0];
    hipMemcpyAsync(d_out, d_in[0], out0_elems * sizeof(float),
                   hipMemcpyDeviceToDevice, stream);

    // workspace: 9 bf16 slots of 2*4096*128 elems (18 MB total)
    const size_t SL = (size_t)2 * 4096 * 128;
    u16* wsu = (u16*)d_ws;
    u16* f1t = wsu + 0 * SL;
    u16* f2t = wsu + 1 * SL;
    u16* f3t = wsu + 2 * SL;
    u16* Qb  = wsu + 3 * SL;
    u16* Kb  = wsu + 4 * SL;
    u16* Vb  = wsu + 5 * SL;
    u16* An  = wsu + 6 * SL;
    u16* A1t = wsu + 7 * SL;
    u16* A2t = wsu + 8 * SL;

    const float LOG2E = 1.44269504088896340736f;

    size_t outOff = out0_elems;
    for (int lvl = 1; lvl <= 3; ++lvl) {
        const int C = CHs[lvl];
        const int Hs = HWs[lvl];
        const int L = Hs * Hs;
        const int dh = C / NHEADS;
        const int M = 2 * L;  // B*L
        const float qscale = LOG2E / sqrtf((float)dh);
        const int bi = 10 + (lvl - 1) * 10;
        const float* a12w  = (const float*)d_in[bi + 0];
        const float* a12b  = (const float*)d_in[bi + 1];
        const float* a12ow = (const float*)d_in[bi + 2];
        const float* a12ob = (const float*)d_in[bi + 3];
        const float* a13w  = (const float*)d_in[bi + 4];
        const float* a13b  = (const float*)d_in[bi + 5];
        const float* a13ow = (const float*)d_in[bi + 6];
        const float* a13ob = (const float*)d_in[bi + 7];
        const float* sqw   = (const float*)d_in[bi + 8];
        const float* sqb   = (const float*)d_in[bi + 9];

        // transpose f1/f2/f3 -> bf16 [b, l, c]
        dim3 tg(L / 32, C / 32, 6);
        transpose_bf16_kernel<<<tg, 256, 0, stream>>>(f1[lvl], f2[lvl], f3[lvl],
                                                      f1t, f2t, f3t, C, L);

        dim3 gq(3 * C / 64, M / 64);
        dim3 gp(C / 64, M / 64);

        // attention 1: Q from f1t, K/V from f2t
        gemm_bf16<0><<<gq, 256, 0, stream>>>(f1t, f2t, nullptr, a12w, a12b,
                                             (void*)Qb, Kb, Vb,
                                             M, 3 * C, C, C, L, dh, qscale);
        run_flash(dh, Qb, Kb, Vb, An, L, stream);
        gemm_bf16<1><<<gp, 256, 0, stream>>>(An, nullptr, nullptr, a12ow, a12ob,
                                             (void*)A1t, nullptr, nullptr,
                                             M, C, C, C, L, dh, 1.0f);

        // attention 2: Q from f1t, K/V from f3t
        gemm_bf16<0><<<gq, 256, 0, stream>>>(f1t, f3t, nullptr, a13w, a13b,
                                             (void*)Qb, Kb, Vb,
                                             M, 3 * C, C, C, L, dh, qscale);
        run_flash(dh, Qb, Kb, Vb, An, L, stream);
        gemm_bf16<1><<<gp, 256, 0, stream>>>(An, nullptr, nullptr, a13ow, a13ob,
                                             (void*)A2t, nullptr, nullptr,
                                             M, C, C, C, L, dh, 1.0f);

        // squeeze into d_out (fp32 [b, n, l])
        gemm_bf16<2><<<gp, 256, 0, stream>>>(f1t, A1t, A2t, sqw, sqb,
                                             (void*)((float*)d_out + outOff),
                                             nullptr, nullptr,
                                             M, C, 3 * C, C, L, dh, 1.0f);
        outOff += (size_t)2 * C * L;
    }
}